// Round 16
// baseline (1292.872 us; speedup 1.0000x reference)
//
#include <hip/hip_runtime.h>
#include <hip/hip_bf16.h>
#include <stdint.h>

#define B_ 4
#define S_ 2048
#define D_ 1024
#define H_ 16
#define L_ 512
#define E_ 8
#define F_ 2048
#define T_ (B_*S_)

typedef __hip_bfloat16 bf16_t;
typedef __attribute__((ext_vector_type(8))) short short8;
typedef __attribute__((ext_vector_type(4))) float f32x4;

__device__ __forceinline__ void gl2lds16(const void* g, void* l) {
  __builtin_amdgcn_global_load_lds(
      reinterpret_cast<const __attribute__((address_space(1))) void*>(reinterpret_cast<uintptr_t>(g)),
      reinterpret_cast<__attribute__((address_space(3))) void*>(reinterpret_cast<uintptr_t>(l)),
      16, 0, 0);
}
__device__ __forceinline__ unsigned short bf16u(bf16_t b) {
  return *reinterpret_cast<unsigned short*>(&b);
}
__device__ __forceinline__ void split2(float v, bf16_t& ho, bf16_t& lo) {
  ho = __float2bfloat16(v);
  lo = __float2bfloat16(v - __bfloat162float(ho));
}
__device__ __forceinline__ float bf2f(bf16_t b) { return __bfloat162float(b); }

// diagnostic-only error path
__global__ __launch_bounds__(256) void k_fill(float* out, float code, int n) {
  int i = blockIdx.x * 256 + threadIdx.x;
  if (i < n) out[i] = (i == 0 ? code : 0.f);
}

// ---- transpose f32 in[r*ldin+c] (R x C) -> bf16 out[c*R+r]; z-batched ----
__global__ __launch_bounds__(256) void k_transpose(const float* __restrict__ in,
                                                   bf16_t* __restrict__ out, int R, int C, int ldin,
                                                   size_t zin, size_t zout) {
  __shared__ float t[32][33];
  const float* inz = in + (size_t)blockIdx.z * zin;
  bf16_t* outz = out + (size_t)blockIdx.z * zout;
  int c0 = blockIdx.x * 32, r0 = blockIdx.y * 32;
  int tx = threadIdx.x, ty = threadIdx.y;
#pragma unroll
  for (int i = 0; i < 4; ++i)
    t[ty + 8*i][tx] = inz[(size_t)(r0 + ty + 8*i) * ldin + c0 + tx];
  __syncthreads();
#pragma unroll
  for (int i = 0; i < 4; ++i)
    outz[(size_t)(c0 + ty + 8*i) * R + r0 + tx] = __float2bfloat16(t[tx][ty + 8*i]);
}

// ---- transpose f32 -> bf16 hi/lo ----
__global__ __launch_bounds__(256) void k_transpose2(const float* __restrict__ in,
                                                    bf16_t* __restrict__ oh, bf16_t* __restrict__ ol,
                                                    int R, int C, int ldin) {
  __shared__ float t[32][33];
  int c0 = blockIdx.x * 32, r0 = blockIdx.y * 32;
  int tx = threadIdx.x, ty = threadIdx.y;
#pragma unroll
  for (int i = 0; i < 4; ++i)
    t[ty + 8*i][tx] = in[(size_t)(r0 + ty + 8*i) * ldin + c0 + tx];
  __syncthreads();
#pragma unroll
  for (int i = 0; i < 4; ++i) {
    float v = t[tx][ty + 8*i];
    size_t idx = (size_t)(c0 + ty + 8*i) * R + r0 + tx;
    bf16_t h, l; split2(v, h, l);
    oh[idx] = h; ol[idx] = l;
  }
}

// ---- rmsnorm(prev)|rmsnorm(fut) -> concat hi/lo bf16 ----
__global__ __launch_bounds__(256) void k_rms2cat2(const float* __restrict__ pa, const float* __restrict__ pb,
                                                  const float* __restrict__ g1, const float* __restrict__ g2,
                                                  bf16_t* __restrict__ oh, bf16_t* __restrict__ ol) {
  const int row = blockIdx.x, tid = threadIdx.x;
  float4 a = reinterpret_cast<const float4*>(pa + (size_t)row * D_)[tid];
  float4 b = reinterpret_cast<const float4*>(pb + (size_t)row * D_)[tid];
  float sa = a.x*a.x + a.y*a.y + a.z*a.z + a.w*a.w;
  float sb = b.x*b.x + b.y*b.y + b.z*b.z + b.w*b.w;
#pragma unroll
  for (int o = 32; o; o >>= 1) { sa += __shfl_xor(sa, o, 64); sb += __shfl_xor(sb, o, 64); }
  __shared__ float red[8];
  if ((tid & 63) == 0) { red[tid >> 6] = sa; red[4 + (tid >> 6)] = sb; }
  __syncthreads();
  sa = red[0] + red[1] + red[2] + red[3];
  sb = red[4] + red[5] + red[6] + red[7];
  float ra = rsqrtf(sa * (1.f / D_) + 1e-6f);
  float rb = rsqrtf(sb * (1.f / D_) + 1e-6f);
  float4 ga = reinterpret_cast<const float4*>(g1)[tid];
  float4 gb = reinterpret_cast<const float4*>(g2)[tid];
  float va[4] = {a.x*ra*ga.x, a.y*ra*ga.y, a.z*ra*ga.z, a.w*ra*ga.w};
  float vb[4] = {b.x*rb*gb.x, b.y*rb*gb.y, b.z*rb*gb.z, b.w*rb*gb.w};
  size_t base = (size_t)row * 2 * D_ + tid * 4;
#pragma unroll
  for (int j = 0; j < 4; ++j) {
    bf16_t h, l;
    split2(va[j], h, l); oh[base + j] = h; ol[base + j] = l;
    split2(vb[j], h, l); oh[base + D_ + j] = h; ol[base + D_ + j] = l;
  }
}

// ---- rmsnorm f32 -> bf16 hi+lo (attn path) ----
__global__ __launch_bounds__(256) void k_rmsnorm2(const float* __restrict__ x, const float* __restrict__ g,
                                                  bf16_t* __restrict__ oh, bf16_t* __restrict__ ol) {
  const int row = blockIdx.x, tid = threadIdx.x;
  float4 v = reinterpret_cast<const float4*>(x + (size_t)row * D_)[tid];
  float ss = v.x*v.x + v.y*v.y + v.z*v.z + v.w*v.w;
#pragma unroll
  for (int o = 32; o; o >>= 1) ss += __shfl_xor(ss, o, 64);
  __shared__ float red[4];
  if ((tid & 63) == 0) red[tid >> 6] = ss;
  __syncthreads();
  ss = red[0] + red[1] + red[2] + red[3];
  float rs = rsqrtf(ss * (1.f / D_) + 1e-6f);
  float4 gv = reinterpret_cast<const float4*>(g)[tid];
  float y[4] = {v.x*rs*gv.x, v.y*rs*gv.y, v.z*rs*gv.z, v.w*rs*gv.w};
  size_t base = (size_t)row * D_ + tid * 4;
#pragma unroll
  for (int j = 0; j < 4; ++j) {
    bf16_t h, l; split2(y[j], h, l);
    oh[base + j] = h;
    ol[base + j] = l;
  }
}

// ---- fused rmsnorm(g_mlp) -> xnh bf16  +  fp32 gate softmax/top2 -> gates [T][8] ----
__global__ __launch_bounds__(256) void k_rmsgate(const float* __restrict__ x, const float* __restrict__ g,
                                                 const float* __restrict__ wg,
                                                 bf16_t* __restrict__ oh, float* __restrict__ gates) {
  const int row = blockIdx.x, tid = threadIdx.x;
  float4 v = reinterpret_cast<const float4*>(x + (size_t)row * D_)[tid];
  float ss = v.x*v.x + v.y*v.y + v.z*v.z + v.w*v.w;
#pragma unroll
  for (int o = 32; o; o >>= 1) ss += __shfl_xor(ss, o, 64);
  __shared__ float red[4];
  __shared__ float eacc[4][8];
  if ((tid & 63) == 0) red[tid >> 6] = ss;
  __syncthreads();
  ss = red[0] + red[1] + red[2] + red[3];
  float rs = rsqrtf(ss * (1.f / D_) + 1e-6f);
  float4 gv = reinterpret_cast<const float4*>(g)[tid];
  float y[4] = {v.x*rs*gv.x, v.y*rs*gv.y, v.z*rs*gv.z, v.w*rs*gv.w};
  size_t base = (size_t)row * D_ + tid * 4;
#pragma unroll
  for (int j = 0; j < 4; ++j) oh[base + j] = __float2bfloat16(y[j]);
  // gate logits
  float acc[8] = {0, 0, 0, 0, 0, 0, 0, 0};
#pragma unroll
  for (int j = 0; j < 4; ++j) {
    const float* wgr = wg + (size_t)(tid * 4 + j) * 8;
#pragma unroll
    for (int e = 0; e < 8; ++e) acc[e] += y[j] * wgr[e];
  }
#pragma unroll
  for (int e = 0; e < 8; ++e) {
#pragma unroll
    for (int o = 32; o; o >>= 1) acc[e] += __shfl_xor(acc[e], o, 64);
  }
  if ((tid & 63) == 0) {
#pragma unroll
    for (int e = 0; e < 8; ++e) eacc[tid >> 6][e] = acc[e];
  }
  __syncthreads();
  if (tid == 0) {
    float a[8];
#pragma unroll
    for (int e = 0; e < 8; ++e) a[e] = eacc[0][e] + eacc[1][e] + eacc[2][e] + eacc[3][e];
    float mx = a[0];
#pragma unroll
    for (int e = 1; e < 8; ++e) mx = fmaxf(mx, a[e]);
    float p[8], sum = 0.f;
#pragma unroll
    for (int e = 0; e < 8; ++e) { p[e] = __expf(a[e] - mx); sum += p[e]; }
#pragma unroll
    for (int e = 0; e < 8; ++e) p[e] /= sum;
    int i0 = 0; float v0 = p[0];
#pragma unroll
    for (int e = 1; e < 8; ++e) if (p[e] > v0) { v0 = p[e]; i0 = e; }
    int i1 = -1; float v1 = -1.f;
#pragma unroll
    for (int e = 0; e < 8; ++e) if (e != i0 && p[e] > v1) { v1 = p[e]; i1 = e; }
    float norm = v0 + v1;
#pragma unroll
    for (int e = 0; e < 8; ++e)
      gates[(size_t)row * 8 + e] = (e == i0) ? v0 / norm : ((e == i1) ? v1 / norm : 0.f);
  }
}

// ---- deterministic routing: per-expert block-scan compaction (token-ordered) ----
__global__ __launch_bounds__(256) void k_route_det(const float* __restrict__ gates,
                                                   int* __restrict__ idx, int* __restrict__ cnt) {
  const int e = blockIdx.x, tid = threadIdx.x;
  __shared__ int sc[256];
  int base = 0;
  for (int c0 = 0; c0 < T_; c0 += 256) {
    int t = c0 + tid;
    int m = (gates[(size_t)t * 8 + e] > 0.f) ? 1 : 0;
    sc[tid] = m;
    __syncthreads();
#pragma unroll
    for (int off = 1; off < 256; off <<= 1) {
      int v = (tid >= off) ? sc[tid - off] : 0;
      __syncthreads();
      sc[tid] += v;
      __syncthreads();
    }
    if (m) idx[e * T_ + base + sc[tid] - 1] = t;
    int tot = sc[255];
    __syncthreads();
    base += tot;
  }
  if (tid == 0) cnt[e] = base;
}

// ---- exclusive prefix of cnt -> off ----
__global__ void k_prefix(const int* __restrict__ cnt, int* __restrict__ off) {
  int s = 0;
  for (int e = 0; e < E_; ++e) { off[e] = s; s += cnt[e]; }
}

// ---- bf16 GEMM (gl2lds + XOR swizzle) ----
// SPLIT=3: hi*hi + hi*lo + lo*hi.  SPLIT=1: hi only.
// IDX=1: A row gathered via aidx[clamp(row)]; early-exit on cnt (NO xcd swizzle -> balance).
// Dense (IDX=0, EPI!=6): XCD-chunked block map for L2 locality (uniform work).
// EPI: 0 Cf=acc, 1 Cf+=acc, 2 split->Cb,Cb2, 3 silu->Cb, 4 Cb*=acc,
//      6 scatter, 7 kv-split
template <int EPI, int SPLIT, int IDX>
__global__ __launch_bounds__(256) void k_sgemm(
    const bf16_t* __restrict__ Ah, const bf16_t* __restrict__ Al,
    const bf16_t* __restrict__ Bh, const bf16_t* __restrict__ Bl,
    float* __restrict__ Cf, bf16_t* __restrict__ Cb, bf16_t* __restrict__ Cb2,
    bf16_t* __restrict__ Cb3, bf16_t* __restrict__ Cb4,
    const float* __restrict__ scale, const int* __restrict__ aidx, const int* __restrict__ cnt,
    int N, int K, int lda, int ldc) {
  __shared__ __align__(16) char lds[(SPLIT == 3 ? 4 : 2) * 16384];
  char* lsAh = lds;
  char* lsBh = lds + 16384;
  char* lsAl = lds + 32768;
  char* lsBl = lds + 49152;
  const int tid = threadIdx.x;
  const int l = tid & 63;
  const int g16 = l >> 4, c16 = l & 15;
  const int nbn = N >> 7;
  int swz = (int)blockIdx.x;
  if constexpr (IDX == 0 && EPI != 6) {
    swz = (swz & 7) * ((int)gridDim.x >> 3) + (swz >> 3);
  }
  const int bm = swz / nbn, bn = swz % nbn;
  const int m0 = bm << 7, n0 = bn << 7;
  const int w = tid >> 6;
  const int wr = w >> 1, wc = w & 1;

  int cval = 0;
  if constexpr (IDX == 1 || EPI == 6) {
    cval = *cnt;
    if (m0 >= cval) return;
  }

  f32x4 acc[4][4] = {};

  int Lb[4], sr[4], sk[4];
#pragma unroll
  for (int i = 0; i < 4; ++i) {
    Lb[i] = (tid + i * 256) * 16;
    sr[i] = Lb[i] >> 7;
    sk[i] = ((Lb[i] & 127) ^ ((sr[i] & 7) << 4)) >> 1;
  }
  int arow[4];
#pragma unroll
  for (int i = 0; i < 4; ++i) {
    if constexpr (IDX == 1) {
      int p = m0 + sr[i];
      arow[i] = aidx[p < cval ? p : cval - 1];
    } else {
      arow[i] = m0 + sr[i];
    }
  }

  for (int k0 = 0; k0 < K; k0 += 64) {
#pragma unroll
    for (int i = 0; i < 4; ++i) {
      size_t aoff = (size_t)arow[i] * lda + k0 + sk[i];
      size_t boff = (size_t)(n0 + sr[i]) * K + k0 + sk[i];
      gl2lds16(Ah + aoff, lsAh + Lb[i]);
      gl2lds16(Bh + boff, lsBh + Lb[i]);
      if constexpr (SPLIT == 3) {
        gl2lds16(Al + aoff, lsAl + Lb[i]);
        gl2lds16(Bl + boff, lsBl + Lb[i]);
      }
    }
    __syncthreads();
#pragma unroll
    for (int kc = 0; kc < 2; ++kc) {
      const int kb = (kc * 32 + 8 * g16) * 2;
      short8 afh[4], bfh[4], afl[4], bfl[4];
#pragma unroll
      for (int m = 0; m < 4; ++m) {
        int row = wr * 64 + m * 16 + c16;
        int off = row * 128 + (kb ^ ((row & 7) << 4));
        afh[m] = *reinterpret_cast<const short8*>(lsAh + off);
        if constexpr (SPLIT == 3) afl[m] = *reinterpret_cast<const short8*>(lsAl + off);
      }
#pragma unroll
      for (int n = 0; n < 4; ++n) {
        int row = wc * 64 + n * 16 + c16;
        int off = row * 128 + (kb ^ ((row & 7) << 4));
        bfh[n] = *reinterpret_cast<const short8*>(lsBh + off);
        if constexpr (SPLIT == 3) bfl[n] = *reinterpret_cast<const short8*>(lsBl + off);
      }
#pragma unroll
      for (int m = 0; m < 4; ++m)
#pragma unroll
        for (int n = 0; n < 4; ++n) {
          if constexpr (SPLIT == 3) {
            acc[m][n] = __builtin_amdgcn_mfma_f32_16x16x32_bf16(afl[m], bfh[n], acc[m][n], 0, 0, 0);
            acc[m][n] = __builtin_amdgcn_mfma_f32_16x16x32_bf16(afh[m], bfl[n], acc[m][n], 0, 0, 0);
          }
          acc[m][n] = __builtin_amdgcn_mfma_f32_16x16x32_bf16(afh[m], bfh[n], acc[m][n], 0, 0, 0);
        }
    }
    __syncthreads();
  }

#pragma unroll
  for (int m = 0; m < 4; ++m) {
    int rb = m0 + wr * 64 + m * 16 + 4 * g16;
#pragma unroll
    for (int n = 0; n < 4; ++n) {
      int gc = n0 + wc * 64 + n * 16 + c16;
#pragma unroll
      for (int r = 0; r < 4; ++r) {
        float v = acc[m][n][r];
        if constexpr (EPI == 6) {
          int rbr = rb + r;
          if (rbr < cval) {
            int tok = aidx[rbr];
            Cf[(size_t)tok * ldc + gc] += scale[(size_t)tok * 8] * v;
          }
        } else if constexpr (EPI == 7) {
          int t = rb + r;
          bf16_t h, lo; split2(v, h, lo);
          if (gc < 1024) {
            size_t ki = (size_t)t * 1024 + gc;
            Cb[ki] = h; Cb2[ki] = lo;
          } else {
            size_t vi = (size_t)(t >> 11) * 2097152 + (size_t)(gc - 1024) * 2048 + (t & 2047);
            Cb3[vi] = h; Cb4[vi] = lo;
          }
        } else {
          size_t idx = (size_t)(rb + r) * ldc + gc;
          if constexpr (EPI == 0) Cf[idx] = v;
          if constexpr (EPI == 1) Cf[idx] += v;
          if constexpr (EPI == 2) { bf16_t h, lo; split2(v, h, lo); Cb[idx] = h; Cb2[idx] = lo; }
          if constexpr (EPI == 3) Cb[idx] = __float2bfloat16(v / (1.f + __expf(-v)));
          if constexpr (EPI == 4) Cb[idx] = __float2bfloat16(bf2f(Cb[idx]) * v);
        }
      }
    }
  }
}

// ---- fused MoE up: hg[off+row][F] = silu(xg@w1^T) * (xg@w3^T); expert = blockIdx.z ----
__global__ __launch_bounds__(256) void k_moe1(
    const bf16_t* __restrict__ xn, const bf16_t* __restrict__ w1t, const bf16_t* __restrict__ w3t,
    bf16_t* __restrict__ hg, const int* __restrict__ idx8, const int* __restrict__ cnt8,
    const int* __restrict__ off8) {
  __shared__ __align__(16) char lds[3 * 16384];
  char* lsA = lds;
  char* lsB1 = lds + 16384;
  char* lsB2 = lds + 32768;
  const int tid = threadIdx.x, l = tid & 63, g16 = l >> 4, c16 = l & 15;
  const int e = blockIdx.z;
  const int nbn = F_ >> 7;
  const int bm = (int)blockIdx.x / nbn, bn = (int)blockIdx.x % nbn;
  const int m0 = bm << 7, n0 = bn << 7;
  const int w = tid >> 6, wr = w >> 1, wc = w & 1;
  const int* aidx = idx8 + e * T_;
  const int cval = cnt8[e];
  if (m0 >= cval) return;
  const int obase = off8[e];
  const bf16_t* B1 = w1t + (size_t)e * D_ * F_;
  const bf16_t* B2 = w3t + (size_t)e * D_ * F_;

  f32x4 a1[4][4] = {}, a3[4][4] = {};
  int Lb[4], sr[4], sk[4], arow[4];
#pragma unroll
  for (int i = 0; i < 4; ++i) {
    Lb[i] = (tid + i * 256) * 16;
    sr[i] = Lb[i] >> 7;
    sk[i] = ((Lb[i] & 127) ^ ((sr[i] & 7) << 4)) >> 1;
    int p = m0 + sr[i];
    arow[i] = aidx[p < cval ? p : cval - 1];
  }
  for (int k0 = 0; k0 < D_; k0 += 64) {
#pragma unroll
    for (int i = 0; i < 4; ++i) {
      gl2lds16(xn + (size_t)arow[i] * D_ + k0 + sk[i], lsA + Lb[i]);
      size_t boff = (size_t)(n0 + sr[i]) * D_ + k0 + sk[i];
      gl2lds16(B1 + boff, lsB1 + Lb[i]);
      gl2lds16(B2 + boff, lsB2 + Lb[i]);
    }
    __syncthreads();
#pragma unroll
    for (int kc = 0; kc < 2; ++kc) {
      const int kb = (kc * 32 + 8 * g16) * 2;
      short8 af[4], b1[4], b2[4];
#pragma unroll
      for (int m = 0; m < 4; ++m) {
        int row = wr * 64 + m * 16 + c16;
        af[m] = *reinterpret_cast<const short8*>(lsA + row * 128 + (kb ^ ((row & 7) << 4)));
      }
#pragma unroll
      for (int n = 0; n < 4; ++n) {
        int row = wc * 64 + n * 16 + c16;
        int off = row * 128 + (kb ^ ((row & 7) << 4));
        b1[n] = *reinterpret_cast<const short8*>(lsB1 + off);
        b2[n] = *reinterpret_cast<const short8*>(lsB2 + off);
      }
#pragma unroll
      for (int m = 0; m < 4; ++m)
#pragma unroll
        for (int n = 0; n < 4; ++n) {
          a1[m][n] = __builtin_amdgcn_mfma_f32_16x16x32_bf16(af[m], b1[n], a1[m][n], 0, 0, 0);
          a3[m][n] = __builtin_amdgcn_mfma_f32_16x16x32_bf16(af[m], b2[n], a3[m][n], 0, 0, 0);
        }
    }
    __syncthreads();
  }
#pragma unroll
  for (int m = 0; m < 4; ++m) {
    int rb = m0 + wr * 64 + m * 16 + 4 * g16;
#pragma unroll
    for (int n = 0; n < 4; ++n) {
      int gc = n0 + wc * 64 + n * 16 + c16;
#pragma unroll
      for (int r = 0; r < 4; ++r) {
        int rbr = rb + r;
        if (rbr < cval) {
          float v1 = a1[m][n][r], v3 = a3[m][n][r];
          hg[(size_t)(obase + rbr) * F_ + gc] = __float2bfloat16(v1 / (1.f + __expf(-v1)) * v3);
        }
      }
    }
  }
}

// ---- MoE down, z-batched over experts; f32 atomicAdd; identity block map ----
__global__ __launch_bounds__(256) void k_moe2z(
    const bf16_t* __restrict__ hg, const bf16_t* __restrict__ w2t,
    float* __restrict__ hid, const float* __restrict__ gates,
    const int* __restrict__ idx8, const int* __restrict__ cnt8, const int* __restrict__ off8) {
  __shared__ __align__(16) char lds[2 * 16384];
  char* lsA = lds;
  char* lsB = lds + 16384;
  const int tid = threadIdx.x, l = tid & 63, g16 = l >> 4, c16 = l & 15;
  const int e = blockIdx.z;
  const int nbn = D_ >> 7;
  const int bm = (int)blockIdx.x / nbn, bn = (int)blockIdx.x % nbn;
  const int m0 = bm << 7, n0 = bn << 7;
  const int w = tid >> 6, wr = w >> 1, wc = w & 1;
  const int* aidx = idx8 + e * T_;
  const int cval = cnt8[e];
  if (m0 >= cval) return;
  const int obase = off8[e];
  const bf16_t* Bt = w2t + (size_t)e * D_ * F_;

  f32x4 acc[4][4] = {};
  int Lb[4], sr[4], sk[4];
#pragma unroll
  for (int i = 0; i < 4; ++i) {
    Lb[i] = (tid + i * 256) * 16;
    sr[i] = Lb[i] >> 7;
    sk[i] = ((Lb[i] & 127) ^ ((sr[i] & 7) << 4)) >> 1;
  }
  for (int k0 = 0; k0 < F_; k0 += 64) {
#pragma unroll
    for (int i = 0; i < 4; ++i) {
      gl2lds16(hg + (size_t)(obase + m0 + sr[i]) * F_ + k0 + sk[i], lsA + Lb[i]);
      gl2lds16(Bt + (size_t)(n0 + sr[i]) * F_ + k0 + sk[i], lsB + Lb[i]);
    }
    __syncthreads();
#pragma unroll
    for (int kc = 0; kc < 2; ++kc) {
      const int kb = (kc * 32 + 8 * g16) * 2;
      short8 af[4], bf8[4];
#pragma unroll
      for (int m = 0; m < 4; ++m) {
        int row = wr * 64 + m * 16 + c16;
        af[m] = *reinterpret_cast<const short8*>(lsA + row * 128 + (kb ^ ((row & 7) << 4)));
      }
#pragma unroll
      for (int n = 0; n < 4; ++n) {
        int row = wc * 64 + n * 16 + c16;
        bf8[n] = *reinterpret_cast<const short8*>(lsB + row * 128 + (kb ^ ((row & 7) << 4)));
      }
#pragma unroll
      for (int m = 0; m < 4; ++m)
#pragma unroll
        for (int n = 0; n < 4; ++n)
          acc[m][n] = __builtin_amdgcn_mfma_f32_16x16x32_bf16(af[m], bf8[n], acc[m][n], 0, 0, 0);
    }
    __syncthreads();
  }
#pragma unroll
  for (int m = 0; m < 4; ++m) {
    int rb = m0 + wr * 64 + m * 16 + 4 * g16;
#pragma unroll
    for (int n = 0; n < 4; ++n) {
      int gc = n0 + wc * 64 + n * 16 + c16;
#pragma unroll
      for (int r = 0; r < 4; ++r) {
        int rbr = rb + r;
        if (rbr < cval) {
          int tok = aidx[rbr];
          atomicAdd(&hid[(size_t)tok * D_ + gc], gates[(size_t)tok * 8 + e] * acc[m][n][r]);
        }
      }
    }
  }
}

// ---- causal flash attention: QBLK=256, 16 waves, split-3, vT-global, dbuf K/V, 1 barrier/tile ----
// Grid: x = h*zb + z (XCD-coherent), y = qt (LPT reversed, 8 values)
// LDS: buf b @ b*32768 {Kh,Kl,Vh,Vl 8KB each}; Ph @65536 + w*2048; Pl @98304 + w*2048 (128KB)
__global__ __launch_bounds__(1024) void k_flash16(
    const bf16_t* __restrict__ qh, const bf16_t* __restrict__ ql,
    const bf16_t* __restrict__ kbh, const bf16_t* __restrict__ kbl,
    const bf16_t* __restrict__ vth, const bf16_t* __restrict__ vtl,
    bf16_t* __restrict__ ch, bf16_t* __restrict__ cl, int zb) {
  __shared__ __align__(16) char lds[131072];
  const int tid = threadIdx.x, l = tid & 63, w = tid >> 6;  // 16 waves
  const int g16 = l >> 4, c16 = l & 15;
  const int qt = (int)gridDim.y - 1 - (int)blockIdx.y;  // LPT: heaviest first
  const int h = (int)blockIdx.x / zb;
  const int z = (int)blockIdx.x % zb;
  const int zS = z * S_;
  const size_t vz = (size_t)z * 2097152;

  const int qrow = qt * 256 + w * 16 + c16;
  const size_t qoff = (size_t)(zS + qrow) * 1536 + h * 64 + 8 * g16;
  const short8 aq0h = *reinterpret_cast<const short8*>(qh + qoff);
  const short8 aq1h = *reinterpret_cast<const short8*>(qh + qoff + 32);
  const short8 aq0l = *reinterpret_cast<const short8*>(ql + qoff);
  const short8 aq1l = *reinterpret_cast<const short8*>(ql + qoff + 32);

  float mrow[4] = {-3e38f, -3e38f, -3e38f, -3e38f};
  float lrow[4] = {0.f, 0.f, 0.f, 0.f};
  f32x4 o[4] = {};
  char* Pwh = lds + 65536 + w * 2048;
  char* Pwl = lds + 98304 + w * 2048;

  auto stage = [&](int buf, int kt) {
    char* base = lds + buf * 32768;
    int t2 = tid & 511;
    int Lb = t2 * 16;
    int r = Lb >> 7;
    int dd = ((Lb & 127) ^ ((r & 7) << 4)) >> 1;
    if (tid < 512) {
      size_t ko = (size_t)(zS + kt * 64 + r) * 1024 + h * 64 + dd;
      gl2lds16(kbh + ko, base + Lb);
      gl2lds16(kbl + ko, base + 8192 + Lb);
    } else {
      size_t vo = vz + (size_t)(h * 64 + r) * 2048 + kt * 64 + dd;
      gl2lds16(vth + vo, base + 16384 + Lb);
      gl2lds16(vtl + vo, base + 24576 + Lb);
    }
  };

  const int nkt = 4 * qt + 4;
  stage(0, 0);
  for (int kt = 0; kt < nkt; ++kt) {
    const int cb = kt & 1;
    char* Kh = lds + cb * 32768;
    char* Kl = Kh + 8192;
    char* Vh = Kh + 16384;
    char* Vl = Kh + 24576;
    __syncthreads();  // buf[cb] drained; all waves done with buf[cb^1]
    if (kt + 1 < nkt) stage(cb ^ 1, kt + 1);  // prefetch flies across compute

    f32x4 s[4] = {};
#pragma unroll
    for (int kc = 0; kc < 2; ++kc) {
      const short8 ah8 = kc ? aq1h : aq0h;
      const short8 al8 = kc ? aq1l : aq0l;
      const int kb = (kc * 32 + 8 * g16) * 2;
#pragma unroll
      for (int n = 0; n < 4; ++n) {
        int row = n * 16 + c16;
        int off = row * 128 + (kb ^ ((row & 7) << 4));
        short8 bkh = *reinterpret_cast<const short8*>(Kh + off);
        short8 bkl = *reinterpret_cast<const short8*>(Kl + off);
        s[n] = __builtin_amdgcn_mfma_f32_16x16x32_bf16(al8, bkh, s[n], 0, 0, 0);
        s[n] = __builtin_amdgcn_mfma_f32_16x16x32_bf16(ah8, bkl, s[n], 0, 0, 0);
        s[n] = __builtin_amdgcn_mfma_f32_16x16x32_bf16(ah8, bkh, s[n], 0, 0, 0);
      }
    }

    const bool dreg = (kt >= 4 * qt);  // only top 4 kv-tiles can cross the diagonal
#pragma unroll
    for (int r = 0; r < 4; ++r) {
      const int rowabs = qt * 256 + w * 16 + 4 * g16 + r;
      float mx = -3e38f;
#pragma unroll
      for (int n = 0; n < 4; ++n) {
        float sv = s[n][r] * 0.125f;
        if (dreg && (kt * 64 + n * 16 + c16 > rowabs)) sv = -3e38f;
        s[n][r] = sv;
        mx = fmaxf(mx, sv);
      }
      mx = fmaxf(mx, __shfl_xor(mx, 1, 64));
      mx = fmaxf(mx, __shfl_xor(mx, 2, 64));
      mx = fmaxf(mx, __shfl_xor(mx, 4, 64));
      mx = fmaxf(mx, __shfl_xor(mx, 8, 64));
      float mnew = fmaxf(mrow[r], mx);
      float alpha = __expf(mrow[r] - mnew);
      float rsum = 0.f;
#pragma unroll
      for (int n = 0; n < 4; ++n) {
        float pp = __expf(s[n][r] - mnew);
        s[n][r] = pp;
        rsum += pp;
      }
      rsum += __shfl_xor(rsum, 1, 64);
      rsum += __shfl_xor(rsum, 2, 64);
      rsum += __shfl_xor(rsum, 4, 64);
      rsum += __shfl_xor(rsum, 8, 64);
      lrow[r] = lrow[r] * alpha + rsum;
      mrow[r] = mnew;
#pragma unroll
      for (int n = 0; n < 4; ++n) o[n][r] *= alpha;
    }

    // P write + read: within-wave-only region -> no barrier
#pragma unroll
    for (int n = 0; n < 4; ++n)
#pragma unroll
      for (int r = 0; r < 4; ++r) {
        int row = 4 * g16 + r, col = n * 16 + c16;
        int off = row * 128 + ((col * 2) ^ ((row & 7) << 4));
        bf16_t ph, pl; split2(s[n][r], ph, pl);
        *reinterpret_cast<unsigned short*>(Pwh + off) = bf16u(ph);
        *reinterpret_cast<unsigned short*>(Pwl + off) = bf16u(pl);
      }

#pragma unroll
    for (int kc = 0; kc < 2; ++kc) {
      const int kb = (kc * 32 + 8 * g16) * 2;
      int poff = c16 * 128 + (kb ^ ((c16 & 7) << 4));
      short8 aph = *reinterpret_cast<const short8*>(Pwh + poff);
      short8 apl = *reinterpret_cast<const short8*>(Pwl + poff);
#pragma unroll
      for (int n = 0; n < 4; ++n) {
        int dr = n * 16 + c16;
        int off = dr * 128 + (kb ^ ((dr & 7) << 4));
        short8 bvh = *reinterpret_cast<const short8*>(Vh + off);
        short8 bvl = *reinterpret_cast<const short8*>(Vl + off);
        o[n] = __builtin_amdgcn_mfma_f32_16x16x32_bf16(apl, bvh, o[n], 0, 0, 0);
        o[n] = __builtin_amdgcn_mfma_f32_16x16x32_bf16(aph, bvl, o[n], 0, 0, 0);
        o[n] = __builtin_amdgcn_mfma_f32_16x16x32_bf16(aph, bvh, o[n], 0, 0, 0);
      }
    }
  }

#pragma unroll
  for (int n = 0; n < 4; ++n)
#pragma unroll
    for (int r = 0; r < 4; ++r) {
      float val = o[n][r] / lrow[r];
      size_t idx = (size_t)(zS + qt * 256 + w * 16 + 4 * g16 + r) * 1024 + h * 64 + n * 16 + c16;
      bf16_t hh, ll; split2(val, hh, ll);
      ch[idx] = hh; cl[idx] = ll;
    }
}

extern "C" void kernel_launch(void* const* d_in, const int* in_sizes, int n_in,
                              void* d_out, int out_size, void* d_ws, size_t ws_size,
                              hipStream_t stream) {
  const size_t MB = 1ull << 20;

  // ---- input-order dispatch by size signature ----
  static const int dictSz[16] = {8388608, 8388608, 2097152, 1024, 1024, 1024, 1024,
                                 1048576, 524288, 524288, 524288, 1048576, 8192,
                                 16777216, 16777216, 16777216};
  static const int alphaSz[16] = {8388608, 1024, 1024, 1024, 1024, 8388608,
                                  16777216, 16777216, 16777216, 2097152, 524288,
                                  8192, 524288, 524288, 1048576, 1048576};
  bool isDict = (n_in == 16), isAlpha = (n_in == 16);
  for (int i = 0; i < 16; ++i) {
    if (n_in != 16) break;
    if (in_sizes[i] != dictSz[i]) isDict = false;
    if (in_sizes[i] != alphaSz[i]) isAlpha = false;
  }
  if ((!isDict && !isAlpha) || ws_size < 64 * MB) {
    k_fill<<<(out_size + 255) / 256, 256, 0, stream>>>((float*)d_out, 444.f, out_size);
    return;
  }

  const float *prev, *fut, *w_combine, *g1, *g2, *g_attn, *g_mlp, *wq, *w_dkv,
      *w_uk, *w_uv, *wo, *w_gate, *w1, *w3, *w2;
  if (isDict) {
    prev = (const float*)d_in[0];  fut = (const float*)d_in[1];
    w_combine = (const float*)d_in[2];
    g1 = (const float*)d_in[3];  g2 = (const float*)d_in[4];
    g_attn = (const float*)d_in[5];  g_mlp = (const float*)d_in[6];
    wq = (const float*)d_in[7];  w_dkv = (const float*)d_in[8];
    w_uk = (const float*)d_in[9];  w_uv = (const float*)d_in[10];
    wo = (const float*)d_in[11];  w_gate = (const float*)d_in[12];
    w1 = (const float*)d_in[13];  w3 = (const float*)d_in[14];
    w2 = (const float*)d_in[15];
  } else {
    fut = (const float*)d_in[0];
    g1 = (const float*)d_in[1];  g2 = (const float*)d_in[2];
    g_attn = (const float*)d_in[3];  g_mlp = (const float*)d_in[4];
    prev = (const float*)d_in[5];
    w1 = (const float*)d_in[6];  w2 = (const float*)d_in[7];  w3 = (const float*)d_in[8];
    w_combine = (const float*)d_in[9];  w_dkv = (const float*)d_in[10];
    w_gate = (const float*)d_in[11];  w_uk = (const float*)d_in[12];
    w_uv = (const float*)d_in[13];  wo = (const float*)d_in[14];
    wq = (const float*)d_in[15];
  }

  float* hid = (float*)d_out;
  char* ws = (char*)d_ws;
  const bool big = (ws_size >= 192 * MB);

  // ---- weights (era-scoped) @ [0,14) ----
  bf16_t* wcth = (bf16_t*)(ws + 0 * MB);
  bf16_t* wctl = (bf16_t*)(ws + 4 * MB);
  bf16_t* qcTh = (bf16_t*)(ws + 0 * MB);
  bf16_t* qcTl = (bf16_t*)(ws + 3 * MB);
  bf16_t* kvTh = (bf16_t*)(ws + 6 * MB);
  bf16_t* kvTl = (bf16_t*)(ws + 8 * MB);
  bf16_t* woth = (bf16_t*)(ws + 10 * MB);
  bf16_t* wotl = (bf16_t*)(ws + 12 * MB);
  bf16_t* w1t  = (bf16_t*)(ws + 0 * MB);   // small path only
  bf16_t* w3t  = (bf16_t*)(ws + 4 * MB);
  bf16_t* w2t  = (bf16_t*)(ws + 8 * MB);
  float*  gates = (float*)(ws + 14 * MB);
  int*    idx   = (int*)(ws + 14 * MB + 262144);
  int*    cnt   = (int*)(ws + 14 * MB + 524288);
  int*    off   = (int*)(ws + 14 * MB + 524288 + 64);
  bf16_t* xnh = (bf16_t*)(ws + 15 * MB);

  dim3 tb(32, 8);

  if (big) {
    // ================= fully batched path (peak 191 MiB) =================
    bf16_t* xcath = (bf16_t*)(ws + 15 * MB);
    bf16_t* xcatl = (bf16_t*)(ws + 47 * MB);
    bf16_t* xnbh  = (bf16_t*)(ws + 15 * MB);
    bf16_t* xnbl  = (bf16_t*)(ws + 31 * MB);
    bf16_t* qch   = (bf16_t*)(ws + 47 * MB);
    bf16_t* qcl   = (bf16_t*)(ws + 71 * MB);
    bf16_t* kbh   = (bf16_t*)(ws + 95 * MB);
    bf16_t* kbl   = (bf16_t*)(ws + 111 * MB);
    bf16_t* vth   = (bf16_t*)(ws + 127 * MB);
    bf16_t* vtl   = (bf16_t*)(ws + 143 * MB);
    bf16_t* ctxh  = (bf16_t*)(ws + 159 * MB);
    bf16_t* ctxl  = (bf16_t*)(ws + 175 * MB);
    // MoE era overlays (after attn consumed)
    bf16_t* hg    = (bf16_t*)(ws + 31 * MB);   // 64 MB
    bf16_t* w1tA  = (bf16_t*)(ws + 95 * MB);   // 32 MB
    bf16_t* w3tA  = (bf16_t*)(ws + 127 * MB);  // 32 MB
    bf16_t* w2tA  = (bf16_t*)(ws + 159 * MB);  // 32 MB

    // combine era
    k_transpose2<<<dim3(32, 64), tb, 0, stream>>>(w_combine, wcth, wctl, 2 * D_, D_, D_);
    k_rms2cat2<<<T_, 256, 0, stream>>>(prev, fut, g1, g2, xcath, xcatl);
    k_sgemm<0, 3, 0><<<dim3(64 * 8), 256, 0, stream>>>(
        xcath, xcatl, wcth, wctl, hid, nullptr, nullptr, nullptr, nullptr,
        nullptr, nullptr, nullptr, D_, 2 * D_, 2 * D_, D_);

    // attn era
    k_transpose2<<<dim3(32, 32), tb, 0, stream>>>(wq, qcTh, qcTl, D_, D_, D_);
    k_transpose2<<<dim3(16, 32), tb, 0, stream>>>(w_dkv, qcTh + 1024 * 1024, qcTl + 1024 * 1024, D_, L_, L_);
    k_transpose2<<<dim3(32, 16), tb, 0, stream>>>(w_uk, kvTh, kvTl, L_, D_, D_);
    k_transpose2<<<dim3(32, 16), tb, 0, stream>>>(w_uv, kvTh + 1024 * 512, kvTl + 1024 * 512, L_, D_, D_);
    k_transpose2<<<dim3(32, 32), tb, 0, stream>>>(wo, woth, wotl, D_, D_, D_);
    k_rmsnorm2<<<T_, 256, 0, stream>>>(hid, g_attn, xnbh, xnbl);
    k_sgemm<2, 3, 0><<<dim3(64 * 12), 256, 0, stream>>>(
        xnbh, xnbl, qcTh, qcTl, nullptr, qch, qcl, nullptr, nullptr,
        nullptr, nullptr, nullptr, 1536, D_, D_, 1536);
    k_sgemm<7, 3, 0><<<dim3(64 * 16), 256, 0, stream>>>(
        qch + 1024, qcl + 1024, kvTh, kvTl, nullptr, kbh, kbl, vth, vtl,
        nullptr, nullptr, nullptr, 2048, L_, 1536, 1024);
    k_flash16<<<dim3(H_ * B_, 8, 1), 1024, 0, stream>>>(qch, qcl, kbh, kbl, vth, vtl, ctxh, ctxl, B_);
    k_sgemm<1, 3, 0><<<dim3(64 * 8), 256, 0, stream>>>(
        ctxh, ctxl, woth, wotl, hid, nullptr, nullptr, nullptr, nullptr,
        nullptr, nullptr, nullptr, D_, D_, D_, D_);

    // MoE era (sparse top-2; deterministic routing; batched weights)
    k_rmsgate<<<T_, 256, 0, stream>>>(hid, g_mlp, w_gate, xnh, gates);
    k_route_det<<<E_, 256, 0, stream>>>(gates, idx, cnt);
    k_prefix<<<1, 1, 0, stream>>>(cnt, off);
    k_transpose<<<dim3(64, 32, 8), tb, 0, stream>>>(w1, w1tA, D_, F_, F_, (size_t)D_ * F_, (size_t)F_ * D_);
    k_transpose<<<dim3(64, 32, 8), tb, 0, stream>>>(w3, w3tA, D_, F_, F_, (size_t)D_ * F_, (size_t)F_ * D_);
    k_transpose<<<dim3(32, 64, 8), tb, 0, stream>>>(w2, w2tA, F_, D_, D_, (size_t)F_ * D_, (size_t)D_ * F_);
    k_moe1<<<dim3(64 * 16, 1, 8), 256, 0, stream>>>(xnh, w1tA, w3tA, hg, idx, cnt, off);
    k_moe2z<<<dim3(64 * 8, 1, 8), 256, 0, stream>>>(hg, w2tA, hid, gates, idx, cnt, off);
  } else {
    // ================= per-batch fallback path (peak 63 MiB) =================
    bf16_t* xcath = (bf16_t*)(ws + 15 * MB);
    bf16_t* xcatl = (bf16_t*)(ws + 23 * MB);
    bf16_t* xnbh  = (bf16_t*)(ws + 15 * MB);
    bf16_t* xnbl  = (bf16_t*)(ws + 19 * MB);
    bf16_t* qch   = (bf16_t*)(ws + 23 * MB);
    bf16_t* qcl   = (bf16_t*)(ws + 29 * MB);
    bf16_t* kbh   = (bf16_t*)(ws + 35 * MB);
    bf16_t* kbl   = (bf16_t*)(ws + 39 * MB);
    bf16_t* vth   = (bf16_t*)(ws + 43 * MB);
    bf16_t* vtl   = (bf16_t*)(ws + 47 * MB);
    bf16_t* ctxh  = (bf16_t*)(ws + 51 * MB);
    bf16_t* ctxl  = (bf16_t*)(ws + 55 * MB);
    bf16_t* hg    = (bf16_t*)(ws + 31 * MB);

    k_transpose2<<<dim3(32, 64), tb, 0, stream>>>(w_combine, wcth, wctl, 2 * D_, D_, D_);
    for (int b = 0; b < B_; ++b) {
      size_t ro = (size_t)b * S_ * D_;
      k_rms2cat2<<<S_, 256, 0, stream>>>(prev + ro, fut + ro, g1, g2, xcath, xcatl);
      k_sgemm<0, 3, 0><<<dim3(16 * 8), 256, 0, stream>>>(
          xcath, xcatl, wcth, wctl, hid + ro, nullptr, nullptr, nullptr, nullptr,
          nullptr, nullptr, nullptr, D_, 2 * D_, 2 * D_, D_);
    }
    k_transpose2<<<dim3(32, 32), tb, 0, stream>>>(wq, qcTh, qcTl, D_, D_, D_);
    k_transpose2<<<dim3(16, 32), tb, 0, stream>>>(w_dkv, qcTh + 1024 * 1024, qcTl + 1024 * 1024, D_, L_, L_);
    k_transpose2<<<dim3(32, 16), tb, 0, stream>>>(w_uk, kvTh, kvTl, L_, D_, D_);
    k_transpose2<<<dim3(32, 16), tb, 0, stream>>>(w_uv, kvTh + 1024 * 512, kvTl + 1024 * 512, L_, D_, D_);
    k_transpose2<<<dim3(32, 32), tb, 0, stream>>>(wo, woth, wotl, D_, D_, D_);
    for (int b = 0; b < B_; ++b) {
      size_t ro = (size_t)b * S_ * D_;
      k_rmsnorm2<<<S_, 256, 0, stream>>>(hid + ro, g_attn, xnbh, xnbl);
      k_sgemm<2, 3, 0><<<dim3(16 * 12), 256, 0, stream>>>(
          xnbh, xnbl, qcTh, qcTl, nullptr, qch, qcl, nullptr, nullptr,
          nullptr, nullptr, nullptr, 1536, D_, D_, 1536);
      k_sgemm<7, 3, 0><<<dim3(16 * 16), 256, 0, stream>>>(
          qch + 1024, qcl + 1024, kvTh, kvTl, nullptr, kbh, kbl, vth, vtl,
          nullptr, nullptr, nullptr, 2048, L_, 1536, 1024);
      k_flash16<<<dim3(H_, 8, 1), 1024, 0, stream>>>(qch, qcl, kbh, kbl, vth, vtl, ctxh, ctxl, 1);
      k_sgemm<1, 3, 0><<<dim3(16 * 8), 256, 0, stream>>>(
          ctxh, ctxl, woth, wotl, hid + ro, nullptr, nullptr, nullptr, nullptr,
          nullptr, nullptr, nullptr, D_, D_, D_, D_);
    }
    k_rmsgate<<<T_, 256, 0, stream>>>(hid, g_mlp, w_gate, xnh, gates);
    k_route_det<<<E_, 256, 0, stream>>>(gates, idx, cnt);
    k_prefix<<<1, 1, 0, stream>>>(cnt, off);
    for (int e = 0; e < E_; ++e) {
      const int* ide = idx + e * T_;
      const int* cne = cnt + e;
      k_transpose<<<dim3(64, 32, 1), tb, 0, stream>>>(w1 + (size_t)e * D_ * F_, w1t, D_, F_, F_, 0, 0);
      k_transpose<<<dim3(64, 32, 1), tb, 0, stream>>>(w3 + (size_t)e * D_ * F_, w3t, D_, F_, F_, 0, 0);
      k_transpose<<<dim3(32, 64, 1), tb, 0, stream>>>(w2 + (size_t)e * F_ * D_, w2t, F_, D_, D_, 0, 0);
      k_sgemm<3, 1, 1><<<dim3(64 * 16), 256, 0, stream>>>(
          xnh, nullptr, w1t, nullptr, nullptr, hg, nullptr, nullptr, nullptr,
          nullptr, ide, cne, F_, D_, D_, F_);
      k_sgemm<4, 1, 1><<<dim3(64 * 16), 256, 0, stream>>>(
          xnh, nullptr, w3t, nullptr, nullptr, hg, nullptr, nullptr, nullptr,
          nullptr, ide, cne, F_, D_, D_, F_);
      k_sgemm<6, 1, 0><<<dim3(64 * 8), 256, 0, stream>>>(
          hg, nullptr, w2t, nullptr, hid, nullptr, nullptr, nullptr, nullptr,
          gates + e, ide, cne, D_, F_, F_, D_);
    }
  }
}

// Round 17
// 1168.045 us; speedup vs baseline: 1.1069x; 1.1069x over previous
//
#include <hip/hip_runtime.h>
#include <hip/hip_bf16.h>
#include <stdint.h>

#define B_ 4
#define S_ 2048
#define D_ 1024
#define H_ 16
#define L_ 512
#define E_ 8
#define F_ 2048
#define T_ (B_*S_)

typedef __hip_bfloat16 bf16_t;
typedef __attribute__((ext_vector_type(8))) short short8;
typedef __attribute__((ext_vector_type(4))) float f32x4;

__device__ __forceinline__ void gl2lds16(const void* g, void* l) {
  __builtin_amdgcn_global_load_lds(
      reinterpret_cast<const __attribute__((address_space(1))) void*>(reinterpret_cast<uintptr_t>(g)),
      reinterpret_cast<__attribute__((address_space(3))) void*>(reinterpret_cast<uintptr_t>(l)),
      16, 0, 0);
}
__device__ __forceinline__ unsigned short bf16u(bf16_t b) {
  return *reinterpret_cast<unsigned short*>(&b);
}
__device__ __forceinline__ void split2(float v, bf16_t& ho, bf16_t& lo) {
  ho = __float2bfloat16(v);
  lo = __float2bfloat16(v - __bfloat162float(ho));
}
__device__ __forceinline__ float bf2f(bf16_t b) { return __bfloat162float(b); }

// diagnostic-only error path
__global__ __launch_bounds__(256) void k_fill(float* out, float code, int n) {
  int i = blockIdx.x * 256 + threadIdx.x;
  if (i < n) out[i] = (i == 0 ? code : 0.f);
}

// ---- transpose f32 in[r*ldin+c] (R x C) -> bf16 out[c*R+r]; z-batched ----
__global__ __launch_bounds__(256) void k_transpose(const float* __restrict__ in,
                                                   bf16_t* __restrict__ out, int R, int C, int ldin,
                                                   size_t zin, size_t zout) {
  __shared__ float t[32][33];
  const float* inz = in + (size_t)blockIdx.z * zin;
  bf16_t* outz = out + (size_t)blockIdx.z * zout;
  int c0 = blockIdx.x * 32, r0 = blockIdx.y * 32;
  int tx = threadIdx.x, ty = threadIdx.y;
#pragma unroll
  for (int i = 0; i < 4; ++i)
    t[ty + 8*i][tx] = inz[(size_t)(r0 + ty + 8*i) * ldin + c0 + tx];
  __syncthreads();
#pragma unroll
  for (int i = 0; i < 4; ++i)
    outz[(size_t)(c0 + ty + 8*i) * R + r0 + tx] = __float2bfloat16(t[tx][ty + 8*i]);
}

// ---- transpose f32 -> bf16 hi/lo ----
__global__ __launch_bounds__(256) void k_transpose2(const float* __restrict__ in,
                                                    bf16_t* __restrict__ oh, bf16_t* __restrict__ ol,
                                                    int R, int C, int ldin) {
  __shared__ float t[32][33];
  int c0 = blockIdx.x * 32, r0 = blockIdx.y * 32;
  int tx = threadIdx.x, ty = threadIdx.y;
#pragma unroll
  for (int i = 0; i < 4; ++i)
    t[ty + 8*i][tx] = in[(size_t)(r0 + ty + 8*i) * ldin + c0 + tx];
  __syncthreads();
#pragma unroll
  for (int i = 0; i < 4; ++i) {
    float v = t[tx][ty + 8*i];
    size_t idx = (size_t)(c0 + ty + 8*i) * R + r0 + tx;
    bf16_t h, l; split2(v, h, l);
    oh[idx] = h; ol[idx] = l;
  }
}

// ---- rmsnorm(prev)|rmsnorm(fut) -> concat hi/lo bf16 ----
__global__ __launch_bounds__(256) void k_rms2cat2(const float* __restrict__ pa, const float* __restrict__ pb,
                                                  const float* __restrict__ g1, const float* __restrict__ g2,
                                                  bf16_t* __restrict__ oh, bf16_t* __restrict__ ol) {
  const int row = blockIdx.x, tid = threadIdx.x;
  float4 a = reinterpret_cast<const float4*>(pa + (size_t)row * D_)[tid];
  float4 b = reinterpret_cast<const float4*>(pb + (size_t)row * D_)[tid];
  float sa = a.x*a.x + a.y*a.y + a.z*a.z + a.w*a.w;
  float sb = b.x*b.x + b.y*b.y + b.z*b.z + b.w*b.w;
#pragma unroll
  for (int o = 32; o; o >>= 1) { sa += __shfl_xor(sa, o, 64); sb += __shfl_xor(sb, o, 64); }
  __shared__ float red[8];
  if ((tid & 63) == 0) { red[tid >> 6] = sa; red[4 + (tid >> 6)] = sb; }
  __syncthreads();
  sa = red[0] + red[1] + red[2] + red[3];
  sb = red[4] + red[5] + red[6] + red[7];
  float ra = rsqrtf(sa * (1.f / D_) + 1e-6f);
  float rb = rsqrtf(sb * (1.f / D_) + 1e-6f);
  float4 ga = reinterpret_cast<const float4*>(g1)[tid];
  float4 gb = reinterpret_cast<const float4*>(g2)[tid];
  float va[4] = {a.x*ra*ga.x, a.y*ra*ga.y, a.z*ra*ga.z, a.w*ra*ga.w};
  float vb[4] = {b.x*rb*gb.x, b.y*rb*gb.y, b.z*rb*gb.z, b.w*rb*gb.w};
  size_t base = (size_t)row * 2 * D_ + tid * 4;
#pragma unroll
  for (int j = 0; j < 4; ++j) {
    bf16_t h, l;
    split2(va[j], h, l); oh[base + j] = h; ol[base + j] = l;
    split2(vb[j], h, l); oh[base + D_ + j] = h; ol[base + D_ + j] = l;
  }
}

// ---- rmsnorm f32 -> bf16 hi+lo (attn path) ----
__global__ __launch_bounds__(256) void k_rmsnorm2(const float* __restrict__ x, const float* __restrict__ g,
                                                  bf16_t* __restrict__ oh, bf16_t* __restrict__ ol) {
  const int row = blockIdx.x, tid = threadIdx.x;
  float4 v = reinterpret_cast<const float4*>(x + (size_t)row * D_)[tid];
  float ss = v.x*v.x + v.y*v.y + v.z*v.z + v.w*v.w;
#pragma unroll
  for (int o = 32; o; o >>= 1) ss += __shfl_xor(ss, o, 64);
  __shared__ float red[4];
  if ((tid & 63) == 0) red[tid >> 6] = ss;
  __syncthreads();
  ss = red[0] + red[1] + red[2] + red[3];
  float rs = rsqrtf(ss * (1.f / D_) + 1e-6f);
  float4 gv = reinterpret_cast<const float4*>(g)[tid];
  float y[4] = {v.x*rs*gv.x, v.y*rs*gv.y, v.z*rs*gv.z, v.w*rs*gv.w};
  size_t base = (size_t)row * D_ + tid * 4;
#pragma unroll
  for (int j = 0; j < 4; ++j) {
    bf16_t h, l; split2(y[j], h, l);
    oh[base + j] = h;
    ol[base + j] = l;
  }
}

// ---- fused rmsnorm(g_mlp) -> xnh bf16  +  fp32 gate softmax/top2 -> gates [T][8] ----
__global__ __launch_bounds__(256) void k_rmsgate(const float* __restrict__ x, const float* __restrict__ g,
                                                 const float* __restrict__ wg,
                                                 bf16_t* __restrict__ oh, float* __restrict__ gates) {
  const int row = blockIdx.x, tid = threadIdx.x;
  float4 v = reinterpret_cast<const float4*>(x + (size_t)row * D_)[tid];
  float ss = v.x*v.x + v.y*v.y + v.z*v.z + v.w*v.w;
#pragma unroll
  for (int o = 32; o; o >>= 1) ss += __shfl_xor(ss, o, 64);
  __shared__ float red[4];
  __shared__ float eacc[4][8];
  if ((tid & 63) == 0) red[tid >> 6] = ss;
  __syncthreads();
  ss = red[0] + red[1] + red[2] + red[3];
  float rs = rsqrtf(ss * (1.f / D_) + 1e-6f);
  float4 gv = reinterpret_cast<const float4*>(g)[tid];
  float y[4] = {v.x*rs*gv.x, v.y*rs*gv.y, v.z*rs*gv.z, v.w*rs*gv.w};
  size_t base = (size_t)row * D_ + tid * 4;
#pragma unroll
  for (int j = 0; j < 4; ++j) oh[base + j] = __float2bfloat16(y[j]);
  float acc[8] = {0, 0, 0, 0, 0, 0, 0, 0};
#pragma unroll
  for (int j = 0; j < 4; ++j) {
    const float* wgr = wg + (size_t)(tid * 4 + j) * 8;
#pragma unroll
    for (int e = 0; e < 8; ++e) acc[e] += y[j] * wgr[e];
  }
#pragma unroll
  for (int e = 0; e < 8; ++e) {
#pragma unroll
    for (int o = 32; o; o >>= 1) acc[e] += __shfl_xor(acc[e], o, 64);
  }
  if ((tid & 63) == 0) {
#pragma unroll
    for (int e = 0; e < 8; ++e) eacc[tid >> 6][e] = acc[e];
  }
  __syncthreads();
  if (tid == 0) {
    float a[8];
#pragma unroll
    for (int e = 0; e < 8; ++e) a[e] = eacc[0][e] + eacc[1][e] + eacc[2][e] + eacc[3][e];
    float mx = a[0];
#pragma unroll
    for (int e = 1; e < 8; ++e) mx = fmaxf(mx, a[e]);
    float p[8], sum = 0.f;
#pragma unroll
    for (int e = 0; e < 8; ++e) { p[e] = __expf(a[e] - mx); sum += p[e]; }
#pragma unroll
    for (int e = 0; e < 8; ++e) p[e] /= sum;
    int i0 = 0; float v0 = p[0];
#pragma unroll
    for (int e = 1; e < 8; ++e) if (p[e] > v0) { v0 = p[e]; i0 = e; }
    int i1 = -1; float v1 = -1.f;
#pragma unroll
    for (int e = 0; e < 8; ++e) if (e != i0 && p[e] > v1) { v1 = p[e]; i1 = e; }
    float norm = v0 + v1;
#pragma unroll
    for (int e = 0; e < 8; ++e)
      gates[(size_t)row * 8 + e] = (e == i0) ? v0 / norm : ((e == i1) ? v1 / norm : 0.f);
  }
}

// ---- deterministic routing: per-expert block-scan compaction; also records pos8[e][t] ----
__global__ __launch_bounds__(256) void k_route_det(const float* __restrict__ gates,
                                                   int* __restrict__ idx, int* __restrict__ cnt,
                                                   int* __restrict__ pos8) {
  const int e = blockIdx.x, tid = threadIdx.x;
  __shared__ int sc[256];
  int base = 0;
  for (int c0 = 0; c0 < T_; c0 += 256) {
    int t = c0 + tid;
    int m = (gates[(size_t)t * 8 + e] > 0.f) ? 1 : 0;
    sc[tid] = m;
    __syncthreads();
#pragma unroll
    for (int off = 1; off < 256; off <<= 1) {
      int v = (tid >= off) ? sc[tid - off] : 0;
      __syncthreads();
      sc[tid] += v;
      __syncthreads();
    }
    if (m) {
      int p = base + sc[tid] - 1;
      idx[e * T_ + p] = t;
      pos8[e * T_ + t] = p;
    }
    int tot = sc[255];
    __syncthreads();
    base += tot;
  }
  if (tid == 0) cnt[e] = base;
}

// ---- exclusive prefix of cnt -> off ----
__global__ void k_prefix(const int* __restrict__ cnt, int* __restrict__ off) {
  int s = 0;
  for (int e = 0; e < E_; ++e) { off[e] = s; s += cnt[e]; }
}

// ---- final MoE sum: hid[t] += sum_e gate[t][e] * hgo[off[e]+pos8[e][t]]  (no atomics) ----
__global__ __launch_bounds__(256) void k_moesum(float* __restrict__ hid, const bf16_t* __restrict__ hgo,
                                                const float* __restrict__ gates,
                                                const int* __restrict__ pos8, const int* __restrict__ off) {
  const int t = blockIdx.x, tid = threadIdx.x;
  size_t hbase = (size_t)t * D_ + tid * 4;
  float4 acc = *reinterpret_cast<const float4*>(hid + hbase);
#pragma unroll
  for (int e = 0; e < 8; ++e) {
    float g = gates[(size_t)t * 8 + e];
    if (g > 0.f) {
      size_t rb = (size_t)(off[e] + pos8[e * T_ + t]) * D_ + tid * 4;
      acc.x += g * bf2f(hgo[rb + 0]);
      acc.y += g * bf2f(hgo[rb + 1]);
      acc.z += g * bf2f(hgo[rb + 2]);
      acc.w += g * bf2f(hgo[rb + 3]);
    }
  }
  *reinterpret_cast<float4*>(hid + hbase) = acc;
}

// ---- bf16 GEMM (gl2lds + XOR swizzle) ----
// SPLIT=3: hi*hi + hi*lo + lo*hi.  SPLIT=1: hi only.
// IDX=1: A row gathered via aidx[clamp(row)]; early-exit on cnt (NO xcd swizzle -> balance).
// Dense (IDX=0, EPI!=6): XCD-chunked block map for L2 locality (uniform work).
// EPI: 0 Cf=acc, 1 Cf+=acc, 2 split->Cb,Cb2, 3 silu->Cb, 4 Cb*=acc, 6 scatter, 7 kv-split
template <int EPI, int SPLIT, int IDX>
__global__ __launch_bounds__(256) void k_sgemm(
    const bf16_t* __restrict__ Ah, const bf16_t* __restrict__ Al,
    const bf16_t* __restrict__ Bh, const bf16_t* __restrict__ Bl,
    float* __restrict__ Cf, bf16_t* __restrict__ Cb, bf16_t* __restrict__ Cb2,
    bf16_t* __restrict__ Cb3, bf16_t* __restrict__ Cb4,
    const float* __restrict__ scale, const int* __restrict__ aidx, const int* __restrict__ cnt,
    int N, int K, int lda, int ldc) {
  __shared__ __align__(16) char lds[(SPLIT == 3 ? 4 : 2) * 16384];
  char* lsAh = lds;
  char* lsBh = lds + 16384;
  char* lsAl = lds + 32768;
  char* lsBl = lds + 49152;
  const int tid = threadIdx.x;
  const int l = tid & 63;
  const int g16 = l >> 4, c16 = l & 15;
  const int nbn = N >> 7;
  int swz = (int)blockIdx.x;
  if constexpr (IDX == 0 && EPI != 6) {
    swz = (swz & 7) * ((int)gridDim.x >> 3) + (swz >> 3);
  }
  const int bm = swz / nbn, bn = swz % nbn;
  const int m0 = bm << 7, n0 = bn << 7;
  const int w = tid >> 6;
  const int wr = w >> 1, wc = w & 1;

  int cval = 0;
  if constexpr (IDX == 1 || EPI == 6) {
    cval = *cnt;
    if (m0 >= cval) return;
  }

  f32x4 acc[4][4] = {};

  int Lb[4], sr[4], sk[4];
#pragma unroll
  for (int i = 0; i < 4; ++i) {
    Lb[i] = (tid + i * 256) * 16;
    sr[i] = Lb[i] >> 7;
    sk[i] = ((Lb[i] & 127) ^ ((sr[i] & 7) << 4)) >> 1;
  }
  int arow[4];
#pragma unroll
  for (int i = 0; i < 4; ++i) {
    if constexpr (IDX == 1) {
      int p = m0 + sr[i];
      arow[i] = aidx[p < cval ? p : cval - 1];
    } else {
      arow[i] = m0 + sr[i];
    }
  }

  for (int k0 = 0; k0 < K; k0 += 64) {
#pragma unroll
    for (int i = 0; i < 4; ++i) {
      size_t aoff = (size_t)arow[i] * lda + k0 + sk[i];
      size_t boff = (size_t)(n0 + sr[i]) * K + k0 + sk[i];
      gl2lds16(Ah + aoff, lsAh + Lb[i]);
      gl2lds16(Bh + boff, lsBh + Lb[i]);
      if constexpr (SPLIT == 3) {
        gl2lds16(Al + aoff, lsAl + Lb[i]);
        gl2lds16(Bl + boff, lsBl + Lb[i]);
      }
    }
    __syncthreads();
#pragma unroll
    for (int kc = 0; kc < 2; ++kc) {
      const int kb = (kc * 32 + 8 * g16) * 2;
      short8 afh[4], bfh[4], afl[4], bfl[4];
#pragma unroll
      for (int m = 0; m < 4; ++m) {
        int row = wr * 64 + m * 16 + c16;
        int off = row * 128 + (kb ^ ((row & 7) << 4));
        afh[m] = *reinterpret_cast<const short8*>(lsAh + off);
        if constexpr (SPLIT == 3) afl[m] = *reinterpret_cast<const short8*>(lsAl + off);
      }
#pragma unroll
      for (int n = 0; n < 4; ++n) {
        int row = wc * 64 + n * 16 + c16;
        int off = row * 128 + (kb ^ ((row & 7) << 4));
        bfh[n] = *reinterpret_cast<const short8*>(lsBh + off);
        if constexpr (SPLIT == 3) bfl[n] = *reinterpret_cast<const short8*>(lsBl + off);
      }
#pragma unroll
      for (int m = 0; m < 4; ++m)
#pragma unroll
        for (int n = 0; n < 4; ++n) {
          if constexpr (SPLIT == 3) {
            acc[m][n] = __builtin_amdgcn_mfma_f32_16x16x32_bf16(afl[m], bfh[n], acc[m][n], 0, 0, 0);
            acc[m][n] = __builtin_amdgcn_mfma_f32_16x16x32_bf16(afh[m], bfl[n], acc[m][n], 0, 0, 0);
          }
          acc[m][n] = __builtin_amdgcn_mfma_f32_16x16x32_bf16(afh[m], bfh[n], acc[m][n], 0, 0, 0);
        }
    }
    __syncthreads();
  }

#pragma unroll
  for (int m = 0; m < 4; ++m) {
    int rb = m0 + wr * 64 + m * 16 + 4 * g16;
#pragma unroll
    for (int n = 0; n < 4; ++n) {
      int gc = n0 + wc * 64 + n * 16 + c16;
#pragma unroll
      for (int r = 0; r < 4; ++r) {
        float v = acc[m][n][r];
        if constexpr (EPI == 6) {
          int rbr = rb + r;
          if (rbr < cval) {
            int tok = aidx[rbr];
            Cf[(size_t)tok * ldc + gc] += scale[(size_t)tok * 8] * v;
          }
        } else if constexpr (EPI == 7) {
          int t = rb + r;
          bf16_t h, lo; split2(v, h, lo);
          if (gc < 1024) {
            size_t ki = (size_t)t * 1024 + gc;
            Cb[ki] = h; Cb2[ki] = lo;
          } else {
            size_t vi = (size_t)(t >> 11) * 2097152 + (size_t)(gc - 1024) * 2048 + (t & 2047);
            Cb3[vi] = h; Cb4[vi] = lo;
          }
        } else {
          size_t idx = (size_t)(rb + r) * ldc + gc;
          if constexpr (EPI == 0) Cf[idx] = v;
          if constexpr (EPI == 1) Cf[idx] += v;
          if constexpr (EPI == 2) { bf16_t h, lo; split2(v, h, lo); Cb[idx] = h; Cb2[idx] = lo; }
          if constexpr (EPI == 3) Cb[idx] = __float2bfloat16(v / (1.f + __expf(-v)));
          if constexpr (EPI == 4) Cb[idx] = __float2bfloat16(bf2f(Cb[idx]) * v);
        }
      }
    }
  }
}

// ---- fused MoE up: hg[off+row][F] = silu(xg@w1^T) * (xg@w3^T); expert = blockIdx.z ----
__global__ __launch_bounds__(256) void k_moe1(
    const bf16_t* __restrict__ xn, const bf16_t* __restrict__ w1t, const bf16_t* __restrict__ w3t,
    bf16_t* __restrict__ hg, const int* __restrict__ idx8, const int* __restrict__ cnt8,
    const int* __restrict__ off8) {
  __shared__ __align__(16) char lds[3 * 16384];
  char* lsA = lds;
  char* lsB1 = lds + 16384;
  char* lsB2 = lds + 32768;
  const int tid = threadIdx.x, l = tid & 63, g16 = l >> 4, c16 = l & 15;
  const int e = blockIdx.z;
  const int nbn = F_ >> 7;
  const int bm = (int)blockIdx.x / nbn, bn = (int)blockIdx.x % nbn;
  const int m0 = bm << 7, n0 = bn << 7;
  const int w = tid >> 6, wr = w >> 1, wc = w & 1;
  const int* aidx = idx8 + e * T_;
  const int cval = cnt8[e];
  if (m0 >= cval) return;
  const int obase = off8[e];
  const bf16_t* B1 = w1t + (size_t)e * D_ * F_;
  const bf16_t* B2 = w3t + (size_t)e * D_ * F_;

  f32x4 a1[4][4] = {}, a3[4][4] = {};
  int Lb[4], sr[4], sk[4], arow[4];
#pragma unroll
  for (int i = 0; i < 4; ++i) {
    Lb[i] = (tid + i * 256) * 16;
    sr[i] = Lb[i] >> 7;
    sk[i] = ((Lb[i] & 127) ^ ((sr[i] & 7) << 4)) >> 1;
    int p = m0 + sr[i];
    arow[i] = aidx[p < cval ? p : cval - 1];
  }
  for (int k0 = 0; k0 < D_; k0 += 64) {
#pragma unroll
    for (int i = 0; i < 4; ++i) {
      gl2lds16(xn + (size_t)arow[i] * D_ + k0 + sk[i], lsA + Lb[i]);
      size_t boff = (size_t)(n0 + sr[i]) * D_ + k0 + sk[i];
      gl2lds16(B1 + boff, lsB1 + Lb[i]);
      gl2lds16(B2 + boff, lsB2 + Lb[i]);
    }
    __syncthreads();
#pragma unroll
    for (int kc = 0; kc < 2; ++kc) {
      const int kb = (kc * 32 + 8 * g16) * 2;
      short8 af[4], b1[4], b2[4];
#pragma unroll
      for (int m = 0; m < 4; ++m) {
        int row = wr * 64 + m * 16 + c16;
        af[m] = *reinterpret_cast<const short8*>(lsA + row * 128 + (kb ^ ((row & 7) << 4)));
      }
#pragma unroll
      for (int n = 0; n < 4; ++n) {
        int row = wc * 64 + n * 16 + c16;
        int off = row * 128 + (kb ^ ((row & 7) << 4));
        b1[n] = *reinterpret_cast<const short8*>(lsB1 + off);
        b2[n] = *reinterpret_cast<const short8*>(lsB2 + off);
      }
#pragma unroll
      for (int m = 0; m < 4; ++m)
#pragma unroll
        for (int n = 0; n < 4; ++n) {
          a1[m][n] = __builtin_amdgcn_mfma_f32_16x16x32_bf16(af[m], b1[n], a1[m][n], 0, 0, 0);
          a3[m][n] = __builtin_amdgcn_mfma_f32_16x16x32_bf16(af[m], b2[n], a3[m][n], 0, 0, 0);
        }
    }
    __syncthreads();
  }
#pragma unroll
  for (int m = 0; m < 4; ++m) {
    int rb = m0 + wr * 64 + m * 16 + 4 * g16;
#pragma unroll
    for (int n = 0; n < 4; ++n) {
      int gc = n0 + wc * 64 + n * 16 + c16;
#pragma unroll
      for (int r = 0; r < 4; ++r) {
        int rbr = rb + r;
        if (rbr < cval) {
          float v1 = a1[m][n][r], v3 = a3[m][n][r];
          hg[(size_t)(obase + rbr) * F_ + gc] = __float2bfloat16(v1 / (1.f + __expf(-v1)) * v3);
        }
      }
    }
  }
}

// ---- MoE down, z-batched; writes compacted hgo rows (no atomics, rows disjoint) ----
__global__ __launch_bounds__(256) void k_moe2w(
    const bf16_t* __restrict__ hg, const bf16_t* __restrict__ w2t,
    bf16_t* __restrict__ hgo,
    const int* __restrict__ cnt8, const int* __restrict__ off8) {
  __shared__ __align__(16) char lds[2 * 16384];
  char* lsA = lds;
  char* lsB = lds + 16384;
  const int tid = threadIdx.x, l = tid & 63, g16 = l >> 4, c16 = l & 15;
  const int e = blockIdx.z;
  const int nbn = D_ >> 7;
  const int bm = (int)blockIdx.x / nbn, bn = (int)blockIdx.x % nbn;
  const int m0 = bm << 7, n0 = bn << 7;
  const int w = tid >> 6, wr = w >> 1, wc = w & 1;
  const int cval = cnt8[e];
  if (m0 >= cval) return;
  const int obase = off8[e];
  const bf16_t* Bt = w2t + (size_t)e * D_ * F_;

  f32x4 acc[4][4] = {};
  int Lb[4], sr[4], sk[4];
#pragma unroll
  for (int i = 0; i < 4; ++i) {
    Lb[i] = (tid + i * 256) * 16;
    sr[i] = Lb[i] >> 7;
    sk[i] = ((Lb[i] & 127) ^ ((sr[i] & 7) << 4)) >> 1;
  }
  for (int k0 = 0; k0 < F_; k0 += 64) {
#pragma unroll
    for (int i = 0; i < 4; ++i) {
      gl2lds16(hg + (size_t)(obase + m0 + sr[i]) * F_ + k0 + sk[i], lsA + Lb[i]);
      gl2lds16(Bt + (size_t)(n0 + sr[i]) * F_ + k0 + sk[i], lsB + Lb[i]);
    }
    __syncthreads();
#pragma unroll
    for (int kc = 0; kc < 2; ++kc) {
      const int kb = (kc * 32 + 8 * g16) * 2;
      short8 af[4], bf8[4];
#pragma unroll
      for (int m = 0; m < 4; ++m) {
        int row = wr * 64 + m * 16 + c16;
        af[m] = *reinterpret_cast<const short8*>(lsA + row * 128 + (kb ^ ((row & 7) << 4)));
      }
#pragma unroll
      for (int n = 0; n < 4; ++n) {
        int row = wc * 64 + n * 16 + c16;
        bf8[n] = *reinterpret_cast<const short8*>(lsB + row * 128 + (kb ^ ((row & 7) << 4)));
      }
#pragma unroll
      for (int m = 0; m < 4; ++m)
#pragma unroll
        for (int n = 0; n < 4; ++n)
          acc[m][n] = __builtin_amdgcn_mfma_f32_16x16x32_bf16(af[m], bf8[n], acc[m][n], 0, 0, 0);
    }
    __syncthreads();
  }
#pragma unroll
  for (int m = 0; m < 4; ++m) {
    int rb = m0 + wr * 64 + m * 16 + 4 * g16;
#pragma unroll
    for (int n = 0; n < 4; ++n) {
      int gc = n0 + wc * 64 + n * 16 + c16;
#pragma unroll
      for (int r = 0; r < 4; ++r) {
        int rbr = rb + r;
        if (rbr < cval)
          hgo[(size_t)(obase + rbr) * D_ + gc] = __float2bfloat16(acc[m][n][r]);
      }
    }
  }
}

// ---- causal flash attention: QBLK=256, 16 waves, split-3, vT-global, dbuf K/V, 1 barrier/tile ----
__global__ __launch_bounds__(1024) void k_flash16(
    const bf16_t* __restrict__ qh, const bf16_t* __restrict__ ql,
    const bf16_t* __restrict__ kbh, const bf16_t* __restrict__ kbl,
    const bf16_t* __restrict__ vth, const bf16_t* __restrict__ vtl,
    bf16_t* __restrict__ ch, bf16_t* __restrict__ cl, int zb) {
  __shared__ __align__(16) char lds[131072];
  const int tid = threadIdx.x, l = tid & 63, w = tid >> 6;  // 16 waves
  const int g16 = l >> 4, c16 = l & 15;
  const int qt = (int)gridDim.y - 1 - (int)blockIdx.y;  // LPT
  const int h = (int)blockIdx.x / zb;
  const int z = (int)blockIdx.x % zb;
  const int zS = z * S_;
  const size_t vz = (size_t)z * 2097152;

  const int qrow = qt * 256 + w * 16 + c16;
  const size_t qoff = (size_t)(zS + qrow) * 1536 + h * 64 + 8 * g16;
  const short8 aq0h = *reinterpret_cast<const short8*>(qh + qoff);
  const short8 aq1h = *reinterpret_cast<const short8*>(qh + qoff + 32);
  const short8 aq0l = *reinterpret_cast<const short8*>(ql + qoff);
  const short8 aq1l = *reinterpret_cast<const short8*>(ql + qoff + 32);

  float mrow[4] = {-3e38f, -3e38f, -3e38f, -3e38f};
  float lrow[4] = {0.f, 0.f, 0.f, 0.f};
  f32x4 o[4] = {};
  char* Pwh = lds + 65536 + w * 2048;
  char* Pwl = lds + 98304 + w * 2048;

  auto stage = [&](int buf, int kt) {
    char* base = lds + buf * 32768;
    int t2 = tid & 511;
    int Lb = t2 * 16;
    int r = Lb >> 7;
    int dd = ((Lb & 127) ^ ((r & 7) << 4)) >> 1;
    if (tid < 512) {
      size_t ko = (size_t)(zS + kt * 64 + r) * 1024 + h * 64 + dd;
      gl2lds16(kbh + ko, base + Lb);
      gl2lds16(kbl + ko, base + 8192 + Lb);
    } else {
      size_t vo = vz + (size_t)(h * 64 + r) * 2048 + kt * 64 + dd;
      gl2lds16(vth + vo, base + 16384 + Lb);
      gl2lds16(vtl + vo, base + 24576 + Lb);
    }
  };

  const int nkt = 4 * qt + 4;
  stage(0, 0);
  for (int kt = 0; kt < nkt; ++kt) {
    const int cb = kt & 1;
    char* Kh = lds + cb * 32768;
    char* Kl = Kh + 8192;
    char* Vh = Kh + 16384;
    char* Vl = Kh + 24576;
    __syncthreads();
    if (kt + 1 < nkt) stage(cb ^ 1, kt + 1);

    f32x4 s[4] = {};
#pragma unroll
    for (int kc = 0; kc < 2; ++kc) {
      const short8 ah8 = kc ? aq1h : aq0h;
      const short8 al8 = kc ? aq1l : aq0l;
      const int kb = (kc * 32 + 8 * g16) * 2;
#pragma unroll
      for (int n = 0; n < 4; ++n) {
        int row = n * 16 + c16;
        int off = row * 128 + (kb ^ ((row & 7) << 4));
        short8 bkh = *reinterpret_cast<const short8*>(Kh + off);
        short8 bkl = *reinterpret_cast<const short8*>(Kl + off);
        s[n] = __builtin_amdgcn_mfma_f32_16x16x32_bf16(al8, bkh, s[n], 0, 0, 0);
        s[n] = __builtin_amdgcn_mfma_f32_16x16x32_bf16(ah8, bkl, s[n], 0, 0, 0);
        s[n] = __builtin_amdgcn_mfma_f32_16x16x32_bf16(ah8, bkh, s[n], 0, 0, 0);
      }
    }

    const bool dreg = (kt >= 4 * qt);
#pragma unroll
    for (int r = 0; r < 4; ++r) {
      const int rowabs = qt * 256 + w * 16 + 4 * g16 + r;
      float mx = -3e38f;
#pragma unroll
      for (int n = 0; n < 4; ++n) {
        float sv = s[n][r] * 0.125f;
        if (dreg && (kt * 64 + n * 16 + c16 > rowabs)) sv = -3e38f;
        s[n][r] = sv;
        mx = fmaxf(mx, sv);
      }
      mx = fmaxf(mx, __shfl_xor(mx, 1, 64));
      mx = fmaxf(mx, __shfl_xor(mx, 2, 64));
      mx = fmaxf(mx, __shfl_xor(mx, 4, 64));
      mx = fmaxf(mx, __shfl_xor(mx, 8, 64));
      float mnew = fmaxf(mrow[r], mx);
      float alpha = __expf(mrow[r] - mnew);
      float rsum = 0.f;
#pragma unroll
      for (int n = 0; n < 4; ++n) {
        float pp = __expf(s[n][r] - mnew);
        s[n][r] = pp;
        rsum += pp;
      }
      rsum += __shfl_xor(rsum, 1, 64);
      rsum += __shfl_xor(rsum, 2, 64);
      rsum += __shfl_xor(rsum, 4, 64);
      rsum += __shfl_xor(rsum, 8, 64);
      lrow[r] = lrow[r] * alpha + rsum;
      mrow[r] = mnew;
#pragma unroll
      for (int n = 0; n < 4; ++n) o[n][r] *= alpha;
    }

#pragma unroll
    for (int n = 0; n < 4; ++n)
#pragma unroll
      for (int r = 0; r < 4; ++r) {
        int row = 4 * g16 + r, col = n * 16 + c16;
        int off = row * 128 + ((col * 2) ^ ((row & 7) << 4));
        bf16_t ph, pl; split2(s[n][r], ph, pl);
        *reinterpret_cast<unsigned short*>(Pwh + off) = bf16u(ph);
        *reinterpret_cast<unsigned short*>(Pwl + off) = bf16u(pl);
      }

#pragma unroll
    for (int kc = 0; kc < 2; ++kc) {
      const int kb = (kc * 32 + 8 * g16) * 2;
      int poff = c16 * 128 + (kb ^ ((c16 & 7) << 4));
      short8 aph = *reinterpret_cast<const short8*>(Pwh + poff);
      short8 apl = *reinterpret_cast<const short8*>(Pwl + poff);
#pragma unroll
      for (int n = 0; n < 4; ++n) {
        int dr = n * 16 + c16;
        int off = dr * 128 + (kb ^ ((dr & 7) << 4));
        short8 bvh = *reinterpret_cast<const short8*>(Vh + off);
        short8 bvl = *reinterpret_cast<const short8*>(Vl + off);
        o[n] = __builtin_amdgcn_mfma_f32_16x16x32_bf16(apl, bvh, o[n], 0, 0, 0);
        o[n] = __builtin_amdgcn_mfma_f32_16x16x32_bf16(aph, bvl, o[n], 0, 0, 0);
        o[n] = __builtin_amdgcn_mfma_f32_16x16x32_bf16(aph, bvh, o[n], 0, 0, 0);
      }
    }
  }

#pragma unroll
  for (int n = 0; n < 4; ++n)
#pragma unroll
    for (int r = 0; r < 4; ++r) {
      float val = o[n][r] / lrow[r];
      size_t idx = (size_t)(zS + qt * 256 + w * 16 + 4 * g16 + r) * 1024 + h * 64 + n * 16 + c16;
      bf16_t hh, ll; split2(val, hh, ll);
      ch[idx] = hh; cl[idx] = ll;
    }
}

extern "C" void kernel_launch(void* const* d_in, const int* in_sizes, int n_in,
                              void* d_out, int out_size, void* d_ws, size_t ws_size,
                              hipStream_t stream) {
  const size_t MB = 1ull << 20;

  // ---- input-order dispatch by size signature ----
  static const int dictSz[16] = {8388608, 8388608, 2097152, 1024, 1024, 1024, 1024,
                                 1048576, 524288, 524288, 524288, 1048576, 8192,
                                 16777216, 16777216, 16777216};
  static const int alphaSz[16] = {8388608, 1024, 1024, 1024, 1024, 8388608,
                                  16777216, 16777216, 16777216, 2097152, 524288,
                                  8192, 524288, 524288, 1048576, 1048576};
  bool isDict = (n_in == 16), isAlpha = (n_in == 16);
  for (int i = 0; i < 16; ++i) {
    if (n_in != 16) break;
    if (in_sizes[i] != dictSz[i]) isDict = false;
    if (in_sizes[i] != alphaSz[i]) isAlpha = false;
  }
  if ((!isDict && !isAlpha) || ws_size < 64 * MB) {
    k_fill<<<(out_size + 255) / 256, 256, 0, stream>>>((float*)d_out, 444.f, out_size);
    return;
  }

  const float *prev, *fut, *w_combine, *g1, *g2, *g_attn, *g_mlp, *wq, *w_dkv,
      *w_uk, *w_uv, *wo, *w_gate, *w1, *w3, *w2;
  if (isDict) {
    prev = (const float*)d_in[0];  fut = (const float*)d_in[1];
    w_combine = (const float*)d_in[2];
    g1 = (const float*)d_in[3];  g2 = (const float*)d_in[4];
    g_attn = (const float*)d_in[5];  g_mlp = (const float*)d_in[6];
    wq = (const float*)d_in[7];  w_dkv = (const float*)d_in[8];
    w_uk = (const float*)d_in[9];  w_uv = (const float*)d_in[10];
    wo = (const float*)d_in[11];  w_gate = (const float*)d_in[12];
    w1 = (const float*)d_in[13];  w3 = (const float*)d_in[14];
    w2 = (const float*)d_in[15];
  } else {
    fut = (const float*)d_in[0];
    g1 = (const float*)d_in[1];  g2 = (const float*)d_in[2];
    g_attn = (const float*)d_in[3];  g_mlp = (const float*)d_in[4];
    prev = (const float*)d_in[5];
    w1 = (const float*)d_in[6];  w2 = (const float*)d_in[7];  w3 = (const float*)d_in[8];
    w_combine = (const float*)d_in[9];  w_dkv = (const float*)d_in[10];
    w_gate = (const float*)d_in[11];  w_uk = (const float*)d_in[12];
    w_uv = (const float*)d_in[13];  wo = (const float*)d_in[14];
    wq = (const float*)d_in[15];
  }

  float* hid = (float*)d_out;
  char* ws = (char*)d_ws;
  const bool big = (ws_size >= 192 * MB);

  // ---- weights (era-scoped) @ [0,14) ----
  bf16_t* wcth = (bf16_t*)(ws + 0 * MB);
  bf16_t* wctl = (bf16_t*)(ws + 4 * MB);
  bf16_t* qcTh = (bf16_t*)(ws + 0 * MB);
  bf16_t* qcTl = (bf16_t*)(ws + 3 * MB);
  bf16_t* kvTh = (bf16_t*)(ws + 6 * MB);
  bf16_t* kvTl = (bf16_t*)(ws + 8 * MB);
  bf16_t* woth = (bf16_t*)(ws + 10 * MB);
  bf16_t* wotl = (bf16_t*)(ws + 12 * MB);
  bf16_t* w1t  = (bf16_t*)(ws + 0 * MB);   // small path only
  bf16_t* w3t  = (bf16_t*)(ws + 4 * MB);
  bf16_t* w2t  = (bf16_t*)(ws + 8 * MB);
  float*  gates = (float*)(ws + 14 * MB);                    // 256KB
  int*    idx   = (int*)(ws + 14 * MB + 262144);             // 256KB
  int*    pos8  = (int*)(ws + 14 * MB + 524288);             // 256KB
  int*    cnt   = (int*)(ws + 14 * MB + 786432);             // 32B
  int*    off   = (int*)(ws + 14 * MB + 786432 + 64);        // 32B
  bf16_t* xnh = (bf16_t*)(ws + 15 * MB);

  dim3 tb(32, 8);

  if (big) {
    // ================= fully batched path (peak 191 MiB) =================
    bf16_t* xcath = (bf16_t*)(ws + 15 * MB);
    bf16_t* xcatl = (bf16_t*)(ws + 47 * MB);
    bf16_t* xnbh  = (bf16_t*)(ws + 15 * MB);
    bf16_t* xnbl  = (bf16_t*)(ws + 31 * MB);
    bf16_t* qch   = (bf16_t*)(ws + 47 * MB);
    bf16_t* qcl   = (bf16_t*)(ws + 71 * MB);
    bf16_t* kbh   = (bf16_t*)(ws + 95 * MB);
    bf16_t* kbl   = (bf16_t*)(ws + 111 * MB);
    bf16_t* vth   = (bf16_t*)(ws + 127 * MB);
    bf16_t* vtl   = (bf16_t*)(ws + 143 * MB);
    bf16_t* ctxh  = (bf16_t*)(ws + 159 * MB);
    bf16_t* ctxl  = (bf16_t*)(ws + 175 * MB);
    // MoE era overlays (after attn consumed)
    bf16_t* hg    = (bf16_t*)(ws + 31 * MB);   // 64 MB  [2T][F]
    bf16_t* hgo   = (bf16_t*)(ws + 95 * MB);   // 32 MB  [2T][D] (w1tA dead by moe2)
    bf16_t* w1tA  = (bf16_t*)(ws + 95 * MB);   // 32 MB (moe1 era only)
    bf16_t* w3tA  = (bf16_t*)(ws + 127 * MB);  // 32 MB
    bf16_t* w2tA  = (bf16_t*)(ws + 159 * MB);  // 32 MB

    // combine era
    k_transpose2<<<dim3(32, 64), tb, 0, stream>>>(w_combine, wcth, wctl, 2 * D_, D_, D_);
    k_rms2cat2<<<T_, 256, 0, stream>>>(prev, fut, g1, g2, xcath, xcatl);
    k_sgemm<0, 3, 0><<<dim3(64 * 8), 256, 0, stream>>>(
        xcath, xcatl, wcth, wctl, hid, nullptr, nullptr, nullptr, nullptr,
        nullptr, nullptr, nullptr, D_, 2 * D_, 2 * D_, D_);

    // attn era
    k_transpose2<<<dim3(32, 32), tb, 0, stream>>>(wq, qcTh, qcTl, D_, D_, D_);
    k_transpose2<<<dim3(16, 32), tb, 0, stream>>>(w_dkv, qcTh + 1024 * 1024, qcTl + 1024 * 1024, D_, L_, L_);
    k_transpose2<<<dim3(32, 16), tb, 0, stream>>>(w_uk, kvTh, kvTl, L_, D_, D_);
    k_transpose2<<<dim3(32, 16), tb, 0, stream>>>(w_uv, kvTh + 1024 * 512, kvTl + 1024 * 512, L_, D_, D_);
    k_transpose2<<<dim3(32, 32), tb, 0, stream>>>(wo, woth, wotl, D_, D_, D_);
    k_rmsnorm2<<<T_, 256, 0, stream>>>(hid, g_attn, xnbh, xnbl);
    k_sgemm<2, 3, 0><<<dim3(64 * 12), 256, 0, stream>>>(
        xnbh, xnbl, qcTh, qcTl, nullptr, qch, qcl, nullptr, nullptr,
        nullptr, nullptr, nullptr, 1536, D_, D_, 1536);
    k_sgemm<7, 3, 0><<<dim3(64 * 16), 256, 0, stream>>>(
        qch + 1024, qcl + 1024, kvTh, kvTl, nullptr, kbh, kbl, vth, vtl,
        nullptr, nullptr, nullptr, 2048, L_, 1536, 1024);
    k_flash16<<<dim3(H_ * B_, 8, 1), 1024, 0, stream>>>(qch, qcl, kbh, kbl, vth, vtl, ctxh, ctxl, B_);
    k_sgemm<1, 3, 0><<<dim3(64 * 8), 256, 0, stream>>>(
        ctxh, ctxl, woth, wotl, hid, nullptr, nullptr, nullptr, nullptr,
        nullptr, nullptr, nullptr, D_, D_, D_, D_);

    // MoE era (sparse top-2; deterministic routing; batched weights; atomic-free down)
    k_rmsgate<<<T_, 256, 0, stream>>>(hid, g_mlp, w_gate, xnh, gates);
    k_route_det<<<E_, 256, 0, stream>>>(gates, idx, cnt, pos8);
    k_prefix<<<1, 1, 0, stream>>>(cnt, off);
    k_transpose<<<dim3(64, 32, 8), tb, 0, stream>>>(w1, w1tA, D_, F_, F_, (size_t)D_ * F_, (size_t)F_ * D_);
    k_transpose<<<dim3(64, 32, 8), tb, 0, stream>>>(w3, w3tA, D_, F_, F_, (size_t)D_ * F_, (size_t)F_ * D_);
    k_transpose<<<dim3(32, 64, 8), tb, 0, stream>>>(w2, w2tA, F_, D_, D_, (size_t)F_ * D_, (size_t)D_ * F_);
    k_moe1<<<dim3(64 * 16, 1, 8), 256, 0, stream>>>(xnh, w1tA, w3tA, hg, idx, cnt, off);
    k_moe2w<<<dim3(64 * 8, 1, 8), 256, 0, stream>>>(hg, w2tA, hgo, cnt, off);
    k_moesum<<<T_, 256, 0, stream>>>(hid, hgo, gates, pos8, off);
  } else {
    // ================= per-batch fallback path (peak 63 MiB) =================
    bf16_t* xcath = (bf16_t*)(ws + 15 * MB);
    bf16_t* xcatl = (bf16_t*)(ws + 23 * MB);
    bf16_t* xnbh  = (bf16_t*)(ws + 15 * MB);
    bf16_t* xnbl  = (bf16_t*)(ws + 19 * MB);
    bf16_t* qch   = (bf16_t*)(ws + 23 * MB);
    bf16_t* qcl   = (bf16_t*)(ws + 29 * MB);
    bf16_t* kbh   = (bf16_t*)(ws + 35 * MB);
    bf16_t* kbl   = (bf16_t*)(ws + 39 * MB);
    bf16_t* vth   = (bf16_t*)(ws + 43 * MB);
    bf16_t* vtl   = (bf16_t*)(ws + 47 * MB);
    bf16_t* ctxh  = (bf16_t*)(ws + 51 * MB);
    bf16_t* ctxl  = (bf16_t*)(ws + 55 * MB);
    bf16_t* hg    = (bf16_t*)(ws + 31 * MB);

    k_transpose2<<<dim3(32, 64), tb, 0, stream>>>(w_combine, wcth, wctl, 2 * D_, D_, D_);
    for (int b = 0; b < B_; ++b) {
      size_t ro = (size_t)b * S_ * D_;
      k_rms2cat2<<<S_, 256, 0, stream>>>(prev + ro, fut + ro, g1, g2, xcath, xcatl);
      k_sgemm<0, 3, 0><<<dim3(16 * 8), 256, 0, stream>>>(
          xcath, xcatl, wcth, wctl, hid + ro, nullptr, nullptr, nullptr, nullptr,
          nullptr, nullptr, nullptr, D_, 2 * D_, 2 * D_, D_);
    }
    k_transpose2<<<dim3(32, 32), tb, 0, stream>>>(wq, qcTh, qcTl, D_, D_, D_);
    k_transpose2<<<dim3(16, 32), tb, 0, stream>>>(w_dkv, qcTh + 1024 * 1024, qcTl + 1024 * 1024, D_, L_, L_);
    k_transpose2<<<dim3(32, 16), tb, 0, stream>>>(w_uk, kvTh, kvTl, L_, D_, D_);
    k_transpose2<<<dim3(32, 16), tb, 0, stream>>>(w_uv, kvTh + 1024 * 512, kvTl + 1024 * 512, L_, D_, D_);
    k_transpose2<<<dim3(32, 32), tb, 0, stream>>>(wo, woth, wotl, D_, D_, D_);
    for (int b = 0; b < B_; ++b) {
      size_t ro = (size_t)b * S_ * D_;
      k_rmsnorm2<<<S_, 256, 0, stream>>>(hid + ro, g_attn, xnbh, xnbl);
      k_sgemm<2, 3, 0><<<dim3(16 * 12), 256, 0, stream>>>(
          xnbh, xnbl, qcTh, qcTl, nullptr, qch, qcl, nullptr, nullptr,
          nullptr, nullptr, nullptr, 1536, D_, D_, 1536);
      k_sgemm<7, 3, 0><<<dim3(16 * 16), 256, 0, stream>>>(
          qch + 1024, qcl + 1024, kvTh, kvTl, nullptr, kbh, kbl, vth, vtl,
          nullptr, nullptr, nullptr, 2048, L_, 1536, 1024);
      k_flash16<<<dim3(H_, 8, 1), 1024, 0, stream>>>(qch, qcl, kbh, kbl, vth, vtl, ctxh, ctxl, 1);
      k_sgemm<1, 3, 0><<<dim3(16 * 8), 256, 0, stream>>>(
          ctxh, ctxl, woth, wotl, hid + ro, nullptr, nullptr, nullptr, nullptr,
          nullptr, nullptr, nullptr, D_, D_, D_, D_);
    }
    k_rmsgate<<<T_, 256, 0, stream>>>(hid, g_mlp, w_gate, xnh, gates);
    k_route_det<<<E_, 256, 0, stream>>>(gates, idx, cnt, pos8);
    k_prefix<<<1, 1, 0, stream>>>(cnt, off);
    for (int e = 0; e < E_; ++e) {
      const int* ide = idx + e * T_;
      const int* cne = cnt + e;
      k_transpose<<<dim3(64, 32, 1), tb, 0, stream>>>(w1 + (size_t)e * D_ * F_, w1t, D_, F_, F_, 0, 0);
      k_transpose<<<dim3(64, 32, 1), tb, 0, stream>>>(w3 + (size_t)e * D_ * F_, w3t, D_, F_, F_, 0, 0);
      k_transpose<<<dim3(32, 64, 1), tb, 0, stream>>>(w2 + (size_t)e * F_ * D_, w2t, F_, D_, D_, 0, 0);
      k_sgemm<3, 1, 1><<<dim3(64 * 16), 256, 0, stream>>>(
          xnh, nullptr, w1t, nullptr, nullptr, hg, nullptr, nullptr, nullptr,
          nullptr, ide, cne, F_, D_, D_, F_);
      k_sgemm<4, 1, 1><<<dim3(64 * 16), 256, 0, stream>>>(
          xnh, nullptr, w3t, nullptr, nullptr, hg, nullptr, nullptr, nullptr,
          nullptr, ide, cne, F_, D_, D_, F_);
      k_sgemm<6, 1, 0><<<dim3(64 * 8), 256, 0, stream>>>(
          hg, nullptr, w2t, nullptr, hid, nullptr, nullptr, nullptr, nullptr,
          gates + e, ide, cne, D_, F_, F_, D_);
    }
  }
}

// Round 18
// 1164.928 us; speedup vs baseline: 1.1098x; 1.0027x over previous
//
#include <hip/hip_runtime.h>
#include <hip/hip_bf16.h>
#include <stdint.h>

#define B_ 4
#define S_ 2048
#define D_ 1024
#define H_ 16
#define L_ 512
#define E_ 8
#define F_ 2048
#define T_ (B_*S_)

typedef __hip_bfloat16 bf16_t;
typedef __attribute__((ext_vector_type(8))) short short8;
typedef __attribute__((ext_vector_type(4))) float f32x4;

__device__ __forceinline__ void gl2lds16(const void* g, void* l) {
  __builtin_amdgcn_global_load_lds(
      reinterpret_cast<const __attribute__((address_space(1))) void*>(reinterpret_cast<uintptr_t>(g)),
      reinterpret_cast<__attribute__((address_space(3))) void*>(reinterpret_cast<uintptr_t>(l)),
      16, 0, 0);
}
__device__ __forceinline__ unsigned short bf16u(bf16_t b) {
  return *reinterpret_cast<unsigned short*>(&b);
}
__device__ __forceinline__ void split2(float v, bf16_t& ho, bf16_t& lo) {
  ho = __float2bfloat16(v);
  lo = __float2bfloat16(v - __bfloat162float(ho));
}
__device__ __forceinline__ float bf2f(bf16_t b) { return __bfloat162float(b); }

// diagnostic-only error path
__global__ __launch_bounds__(256) void k_fill(float* out, float code, int n) {
  int i = blockIdx.x * 256 + threadIdx.x;
  if (i < n) out[i] = (i == 0 ? code : 0.f);
}

// ---- transpose f32 in[r*ldin+c] (R x C) -> bf16 out[c*R+r]; z-batched ----
__global__ __launch_bounds__(256) void k_transpose(const float* __restrict__ in,
                                                   bf16_t* __restrict__ out, int R, int C, int ldin,
                                                   size_t zin, size_t zout) {
  __shared__ float t[32][33];
  const float* inz = in + (size_t)blockIdx.z * zin;
  bf16_t* outz = out + (size_t)blockIdx.z * zout;
  int c0 = blockIdx.x * 32, r0 = blockIdx.y * 32;
  int tx = threadIdx.x, ty = threadIdx.y;
#pragma unroll
  for (int i = 0; i < 4; ++i)
    t[ty + 8*i][tx] = inz[(size_t)(r0 + ty + 8*i) * ldin + c0 + tx];
  __syncthreads();
#pragma unroll
  for (int i = 0; i < 4; ++i)
    outz[(size_t)(c0 + ty + 8*i) * R + r0 + tx] = __float2bfloat16(t[tx][ty + 8*i]);
}

// ---- paired transpose: z<8 -> w1 from inA, z>=8 -> w3 from inB (same geometry) ----
__global__ __launch_bounds__(256) void k_transpose_pair(const float* __restrict__ inA,
                                                        const float* __restrict__ inB,
                                                        bf16_t* __restrict__ outA,
                                                        bf16_t* __restrict__ outB,
                                                        int R, int C, int ldin,
                                                        size_t zin, size_t zout) {
  __shared__ float t[32][33];
  int z = blockIdx.z;
  const float* inz = (z < 8 ? inA + (size_t)z * zin : inB + (size_t)(z - 8) * zin);
  bf16_t* outz = (z < 8 ? outA + (size_t)z * zout : outB + (size_t)(z - 8) * zout);
  int c0 = blockIdx.x * 32, r0 = blockIdx.y * 32;
  int tx = threadIdx.x, ty = threadIdx.y;
#pragma unroll
  for (int i = 0; i < 4; ++i)
    t[ty + 8*i][tx] = inz[(size_t)(r0 + ty + 8*i) * ldin + c0 + tx];
  __syncthreads();
#pragma unroll
  for (int i = 0; i < 4; ++i)
    outz[(size_t)(c0 + ty + 8*i) * R + r0 + tx] = __float2bfloat16(t[tx][ty + 8*i]);
}

// ---- transpose f32 -> bf16 hi/lo ----
__global__ __launch_bounds__(256) void k_transpose2(const float* __restrict__ in,
                                                    bf16_t* __restrict__ oh, bf16_t* __restrict__ ol,
                                                    int R, int C, int ldin) {
  __shared__ float t[32][33];
  int c0 = blockIdx.x * 32, r0 = blockIdx.y * 32;
  int tx = threadIdx.x, ty = threadIdx.y;
#pragma unroll
  for (int i = 0; i < 4; ++i)
    t[ty + 8*i][tx] = in[(size_t)(r0 + ty + 8*i) * ldin + c0 + tx];
  __syncthreads();
#pragma unroll
  for (int i = 0; i < 4; ++i) {
    float v = t[tx][ty + 8*i];
    size_t idx = (size_t)(c0 + ty + 8*i) * R + r0 + tx;
    bf16_t h, l; split2(v, h, l);
    oh[idx] = h; ol[idx] = l;
  }
}

// ---- rmsnorm(prev)|rmsnorm(fut) -> concat hi/lo bf16 ----
__global__ __launch_bounds__(256) void k_rms2cat2(const float* __restrict__ pa, const float* __restrict__ pb,
                                                  const float* __restrict__ g1, const float* __restrict__ g2,
                                                  bf16_t* __restrict__ oh, bf16_t* __restrict__ ol) {
  const int row = blockIdx.x, tid = threadIdx.x;
  float4 a = reinterpret_cast<const float4*>(pa + (size_t)row * D_)[tid];
  float4 b = reinterpret_cast<const float4*>(pb + (size_t)row * D_)[tid];
  float sa = a.x*a.x + a.y*a.y + a.z*a.z + a.w*a.w;
  float sb = b.x*b.x + b.y*b.y + b.z*b.z + b.w*b.w;
#pragma unroll
  for (int o = 32; o; o >>= 1) { sa += __shfl_xor(sa, o, 64); sb += __shfl_xor(sb, o, 64); }
  __shared__ float red[8];
  if ((tid & 63) == 0) { red[tid >> 6] = sa; red[4 + (tid >> 6)] = sb; }
  __syncthreads();
  sa = red[0] + red[1] + red[2] + red[3];
  sb = red[4] + red[5] + red[6] + red[7];
  float ra = rsqrtf(sa * (1.f / D_) + 1e-6f);
  float rb = rsqrtf(sb * (1.f / D_) + 1e-6f);
  float4 ga = reinterpret_cast<const float4*>(g1)[tid];
  float4 gb = reinterpret_cast<const float4*>(g2)[tid];
  float va[4] = {a.x*ra*ga.x, a.y*ra*ga.y, a.z*ra*ga.z, a.w*ra*ga.w};
  float vb[4] = {b.x*rb*gb.x, b.y*rb*gb.y, b.z*rb*gb.z, b.w*rb*gb.w};
  size_t base = (size_t)row * 2 * D_ + tid * 4;
#pragma unroll
  for (int j = 0; j < 4; ++j) {
    bf16_t h, l;
    split2(va[j], h, l); oh[base + j] = h; ol[base + j] = l;
    split2(vb[j], h, l); oh[base + D_ + j] = h; ol[base + D_ + j] = l;
  }
}

// ---- rmsnorm f32 -> bf16 hi+lo (attn path) ----
__global__ __launch_bounds__(256) void k_rmsnorm2(const float* __restrict__ x, const float* __restrict__ g,
                                                  bf16_t* __restrict__ oh, bf16_t* __restrict__ ol) {
  const int row = blockIdx.x, tid = threadIdx.x;
  float4 v = reinterpret_cast<const float4*>(x + (size_t)row * D_)[tid];
  float ss = v.x*v.x + v.y*v.y + v.z*v.z + v.w*v.w;
#pragma unroll
  for (int o = 32; o; o >>= 1) ss += __shfl_xor(ss, o, 64);
  __shared__ float red[4];
  if ((tid & 63) == 0) red[tid >> 6] = ss;
  __syncthreads();
  ss = red[0] + red[1] + red[2] + red[3];
  float rs = rsqrtf(ss * (1.f / D_) + 1e-6f);
  float4 gv = reinterpret_cast<const float4*>(g)[tid];
  float y[4] = {v.x*rs*gv.x, v.y*rs*gv.y, v.z*rs*gv.z, v.w*rs*gv.w};
  size_t base = (size_t)row * D_ + tid * 4;
#pragma unroll
  for (int j = 0; j < 4; ++j) {
    bf16_t h, l; split2(y[j], h, l);
    oh[base + j] = h;
    ol[base + j] = l;
  }
}

// ---- fused rmsnorm(g_mlp) -> xnh bf16  +  fp32 gate softmax/top2 -> gates [T][8] ----
__global__ __launch_bounds__(256) void k_rmsgate(const float* __restrict__ x, const float* __restrict__ g,
                                                 const float* __restrict__ wg,
                                                 bf16_t* __restrict__ oh, float* __restrict__ gates) {
  const int row = blockIdx.x, tid = threadIdx.x;
  float4 v = reinterpret_cast<const float4*>(x + (size_t)row * D_)[tid];
  float ss = v.x*v.x + v.y*v.y + v.z*v.z + v.w*v.w;
#pragma unroll
  for (int o = 32; o; o >>= 1) ss += __shfl_xor(ss, o, 64);
  __shared__ float red[4];
  __shared__ float eacc[4][8];
  if ((tid & 63) == 0) red[tid >> 6] = ss;
  __syncthreads();
  ss = red[0] + red[1] + red[2] + red[3];
  float rs = rsqrtf(ss * (1.f / D_) + 1e-6f);
  float4 gv = reinterpret_cast<const float4*>(g)[tid];
  float y[4] = {v.x*rs*gv.x, v.y*rs*gv.y, v.z*rs*gv.z, v.w*rs*gv.w};
  size_t base = (size_t)row * D_ + tid * 4;
#pragma unroll
  for (int j = 0; j < 4; ++j) oh[base + j] = __float2bfloat16(y[j]);
  float acc[8] = {0, 0, 0, 0, 0, 0, 0, 0};
#pragma unroll
  for (int j = 0; j < 4; ++j) {
    const float* wgr = wg + (size_t)(tid * 4 + j) * 8;
#pragma unroll
    for (int e = 0; e < 8; ++e) acc[e] += y[j] * wgr[e];
  }
#pragma unroll
  for (int e = 0; e < 8; ++e) {
#pragma unroll
    for (int o = 32; o; o >>= 1) acc[e] += __shfl_xor(acc[e], o, 64);
  }
  if ((tid & 63) == 0) {
#pragma unroll
    for (int e = 0; e < 8; ++e) eacc[tid >> 6][e] = acc[e];
  }
  __syncthreads();
  if (tid == 0) {
    float a[8];
#pragma unroll
    for (int e = 0; e < 8; ++e) a[e] = eacc[0][e] + eacc[1][e] + eacc[2][e] + eacc[3][e];
    float mx = a[0];
#pragma unroll
    for (int e = 1; e < 8; ++e) mx = fmaxf(mx, a[e]);
    float p[8], sum = 0.f;
#pragma unroll
    for (int e = 0; e < 8; ++e) { p[e] = __expf(a[e] - mx); sum += p[e]; }
#pragma unroll
    for (int e = 0; e < 8; ++e) p[e] /= sum;
    int i0 = 0; float v0 = p[0];
#pragma unroll
    for (int e = 1; e < 8; ++e) if (p[e] > v0) { v0 = p[e]; i0 = e; }
    int i1 = -1; float v1 = -1.f;
#pragma unroll
    for (int e = 0; e < 8; ++e) if (e != i0 && p[e] > v1) { v1 = p[e]; i1 = e; }
    float norm = v0 + v1;
#pragma unroll
    for (int e = 0; e < 8; ++e)
      gates[(size_t)row * 8 + e] = (e == i0) ? v0 / norm : ((e == i1) ? v1 / norm : 0.f);
  }
}

// ---- deterministic routing: per-expert block-scan compaction; also records pos8[e][t] ----
__global__ __launch_bounds__(256) void k_route_det(const float* __restrict__ gates,
                                                   int* __restrict__ idx, int* __restrict__ cnt,
                                                   int* __restrict__ pos8) {
  const int e = blockIdx.x, tid = threadIdx.x;
  __shared__ int sc[256];
  int base = 0;
  for (int c0 = 0; c0 < T_; c0 += 256) {
    int t = c0 + tid;
    int m = (gates[(size_t)t * 8 + e] > 0.f) ? 1 : 0;
    sc[tid] = m;
    __syncthreads();
#pragma unroll
    for (int off = 1; off < 256; off <<= 1) {
      int v = (tid >= off) ? sc[tid - off] : 0;
      __syncthreads();
      sc[tid] += v;
      __syncthreads();
    }
    if (m) {
      int p = base + sc[tid] - 1;
      idx[e * T_ + p] = t;
      pos8[e * T_ + t] = p;
    }
    int tot = sc[255];
    __syncthreads();
    base += tot;
  }
  if (tid == 0) cnt[e] = base;
}

// ---- exclusive prefix of cnt -> off ----
__global__ void k_prefix(const int* __restrict__ cnt, int* __restrict__ off) {
  int s = 0;
  for (int e = 0; e < E_; ++e) { off[e] = s; s += cnt[e]; }
}

// ---- final MoE sum: hid[t] += sum_e gate[t][e] * hgo[off[e]+pos8[e][t]]  (no atomics) ----
__global__ __launch_bounds__(256) void k_moesum(float* __restrict__ hid, const bf16_t* __restrict__ hgo,
                                                const float* __restrict__ gates,
                                                const int* __restrict__ pos8, const int* __restrict__ off) {
  const int t = blockIdx.x, tid = threadIdx.x;
  size_t hbase = (size_t)t * D_ + tid * 4;
  float4 acc = *reinterpret_cast<const float4*>(hid + hbase);
#pragma unroll
  for (int e = 0; e < 8; ++e) {
    float g = gates[(size_t)t * 8 + e];
    if (g > 0.f) {
      size_t rb = (size_t)(off[e] + pos8[e * T_ + t]) * D_ + tid * 4;
      acc.x += g * bf2f(hgo[rb + 0]);
      acc.y += g * bf2f(hgo[rb + 1]);
      acc.z += g * bf2f(hgo[rb + 2]);
      acc.w += g * bf2f(hgo[rb + 3]);
    }
  }
  *reinterpret_cast<float4*>(hid + hbase) = acc;
}

// ---- bf16 GEMM (gl2lds + XOR swizzle) ----
// SPLIT=3: hi*hi + hi*lo + lo*hi.  SPLIT=1: hi only.
// IDX=1: A row gathered via aidx[clamp(row)]; early-exit on cnt (NO xcd swizzle -> balance).
// Dense (IDX=0, EPI!=6): XCD-chunked block map for L2 locality (uniform work).
// EPI: 0 Cf=acc, 1 Cf+=acc, 2 split->Cb,Cb2, 3 silu->Cb, 4 Cb*=acc, 6 scatter, 7 kv-split
template <int EPI, int SPLIT, int IDX>
__global__ __launch_bounds__(256) void k_sgemm(
    const bf16_t* __restrict__ Ah, const bf16_t* __restrict__ Al,
    const bf16_t* __restrict__ Bh, const bf16_t* __restrict__ Bl,
    float* __restrict__ Cf, bf16_t* __restrict__ Cb, bf16_t* __restrict__ Cb2,
    bf16_t* __restrict__ Cb3, bf16_t* __restrict__ Cb4,
    const float* __restrict__ scale, const int* __restrict__ aidx, const int* __restrict__ cnt,
    int N, int K, int lda, int ldc) {
  __shared__ __align__(16) char lds[(SPLIT == 3 ? 4 : 2) * 16384];
  char* lsAh = lds;
  char* lsBh = lds + 16384;
  char* lsAl = lds + 32768;
  char* lsBl = lds + 49152;
  const int tid = threadIdx.x;
  const int l = tid & 63;
  const int g16 = l >> 4, c16 = l & 15;
  const int nbn = N >> 7;
  int swz = (int)blockIdx.x;
  if constexpr (IDX == 0 && EPI != 6) {
    swz = (swz & 7) * ((int)gridDim.x >> 3) + (swz >> 3);
  }
  const int bm = swz / nbn, bn = swz % nbn;
  const int m0 = bm << 7, n0 = bn << 7;
  const int w = tid >> 6;
  const int wr = w >> 1, wc = w & 1;

  int cval = 0;
  if constexpr (IDX == 1 || EPI == 6) {
    cval = *cnt;
    if (m0 >= cval) return;
  }

  f32x4 acc[4][4] = {};

  int Lb[4], sr[4], sk[4];
#pragma unroll
  for (int i = 0; i < 4; ++i) {
    Lb[i] = (tid + i * 256) * 16;
    sr[i] = Lb[i] >> 7;
    sk[i] = ((Lb[i] & 127) ^ ((sr[i] & 7) << 4)) >> 1;
  }
  int arow[4];
#pragma unroll
  for (int i = 0; i < 4; ++i) {
    if constexpr (IDX == 1) {
      int p = m0 + sr[i];
      arow[i] = aidx[p < cval ? p : cval - 1];
    } else {
      arow[i] = m0 + sr[i];
    }
  }

  for (int k0 = 0; k0 < K; k0 += 64) {
#pragma unroll
    for (int i = 0; i < 4; ++i) {
      size_t aoff = (size_t)arow[i] * lda + k0 + sk[i];
      size_t boff = (size_t)(n0 + sr[i]) * K + k0 + sk[i];
      gl2lds16(Ah + aoff, lsAh + Lb[i]);
      gl2lds16(Bh + boff, lsBh + Lb[i]);
      if constexpr (SPLIT == 3) {
        gl2lds16(Al + aoff, lsAl + Lb[i]);
        gl2lds16(Bl + boff, lsBl + Lb[i]);
      }
    }
    __syncthreads();
#pragma unroll
    for (int kc = 0; kc < 2; ++kc) {
      const int kb = (kc * 32 + 8 * g16) * 2;
      short8 afh[4], bfh[4], afl[4], bfl[4];
#pragma unroll
      for (int m = 0; m < 4; ++m) {
        int row = wr * 64 + m * 16 + c16;
        int off = row * 128 + (kb ^ ((row & 7) << 4));
        afh[m] = *reinterpret_cast<const short8*>(lsAh + off);
        if constexpr (SPLIT == 3) afl[m] = *reinterpret_cast<const short8*>(lsAl + off);
      }
#pragma unroll
      for (int n = 0; n < 4; ++n) {
        int row = wc * 64 + n * 16 + c16;
        int off = row * 128 + (kb ^ ((row & 7) << 4));
        bfh[n] = *reinterpret_cast<const short8*>(lsBh + off);
        if constexpr (SPLIT == 3) bfl[n] = *reinterpret_cast<const short8*>(lsBl + off);
      }
#pragma unroll
      for (int m = 0; m < 4; ++m)
#pragma unroll
        for (int n = 0; n < 4; ++n) {
          if constexpr (SPLIT == 3) {
            acc[m][n] = __builtin_amdgcn_mfma_f32_16x16x32_bf16(afl[m], bfh[n], acc[m][n], 0, 0, 0);
            acc[m][n] = __builtin_amdgcn_mfma_f32_16x16x32_bf16(afh[m], bfl[n], acc[m][n], 0, 0, 0);
          }
          acc[m][n] = __builtin_amdgcn_mfma_f32_16x16x32_bf16(afh[m], bfh[n], acc[m][n], 0, 0, 0);
        }
    }
    __syncthreads();
  }

#pragma unroll
  for (int m = 0; m < 4; ++m) {
    int rb = m0 + wr * 64 + m * 16 + 4 * g16;
#pragma unroll
    for (int n = 0; n < 4; ++n) {
      int gc = n0 + wc * 64 + n * 16 + c16;
#pragma unroll
      for (int r = 0; r < 4; ++r) {
        float v = acc[m][n][r];
        if constexpr (EPI == 6) {
          int rbr = rb + r;
          if (rbr < cval) {
            int tok = aidx[rbr];
            Cf[(size_t)tok * ldc + gc] += scale[(size_t)tok * 8] * v;
          }
        } else if constexpr (EPI == 7) {
          int t = rb + r;
          bf16_t h, lo; split2(v, h, lo);
          if (gc < 1024) {
            size_t ki = (size_t)t * 1024 + gc;
            Cb[ki] = h; Cb2[ki] = lo;
          } else {
            size_t vi = (size_t)(t >> 11) * 2097152 + (size_t)(gc - 1024) * 2048 + (t & 2047);
            Cb3[vi] = h; Cb4[vi] = lo;
          }
        } else {
          size_t idx = (size_t)(rb + r) * ldc + gc;
          if constexpr (EPI == 0) Cf[idx] = v;
          if constexpr (EPI == 1) Cf[idx] += v;
          if constexpr (EPI == 2) { bf16_t h, lo; split2(v, h, lo); Cb[idx] = h; Cb2[idx] = lo; }
          if constexpr (EPI == 3) Cb[idx] = __float2bfloat16(v / (1.f + __expf(-v)));
          if constexpr (EPI == 4) Cb[idx] = __float2bfloat16(bf2f(Cb[idx]) * v);
        }
      }
    }
  }
}

// ---- fused MoE up: hg[off+row][F] = silu(xg@w1^T) * (xg@w3^T); expert = blockIdx.z ----
__global__ __launch_bounds__(256) void k_moe1(
    const bf16_t* __restrict__ xn, const bf16_t* __restrict__ w1t, const bf16_t* __restrict__ w3t,
    bf16_t* __restrict__ hg, const int* __restrict__ idx8, const int* __restrict__ cnt8,
    const int* __restrict__ off8) {
  __shared__ __align__(16) char lds[3 * 16384];
  char* lsA = lds;
  char* lsB1 = lds + 16384;
  char* lsB2 = lds + 32768;
  const int tid = threadIdx.x, l = tid & 63, g16 = l >> 4, c16 = l & 15;
  const int e = blockIdx.z;
  const int nbn = F_ >> 7;
  const int bm = (int)blockIdx.x / nbn, bn = (int)blockIdx.x % nbn;
  const int m0 = bm << 7, n0 = bn << 7;
  const int w = tid >> 6, wr = w >> 1, wc = w & 1;
  const int* aidx = idx8 + e * T_;
  const int cval = cnt8[e];
  if (m0 >= cval) return;
  const int obase = off8[e];
  const bf16_t* B1 = w1t + (size_t)e * D_ * F_;
  const bf16_t* B2 = w3t + (size_t)e * D_ * F_;

  f32x4 a1[4][4] = {}, a3[4][4] = {};
  int Lb[4], sr[4], sk[4], arow[4];
#pragma unroll
  for (int i = 0; i < 4; ++i) {
    Lb[i] = (tid + i * 256) * 16;
    sr[i] = Lb[i] >> 7;
    sk[i] = ((Lb[i] & 127) ^ ((sr[i] & 7) << 4)) >> 1;
    int p = m0 + sr[i];
    arow[i] = aidx[p < cval ? p : cval - 1];
  }
  for (int k0 = 0; k0 < D_; k0 += 64) {
#pragma unroll
    for (int i = 0; i < 4; ++i) {
      gl2lds16(xn + (size_t)arow[i] * D_ + k0 + sk[i], lsA + Lb[i]);
      size_t boff = (size_t)(n0 + sr[i]) * D_ + k0 + sk[i];
      gl2lds16(B1 + boff, lsB1 + Lb[i]);
      gl2lds16(B2 + boff, lsB2 + Lb[i]);
    }
    __syncthreads();
#pragma unroll
    for (int kc = 0; kc < 2; ++kc) {
      const int kb = (kc * 32 + 8 * g16) * 2;
      short8 af[4], b1[4], b2[4];
#pragma unroll
      for (int m = 0; m < 4; ++m) {
        int row = wr * 64 + m * 16 + c16;
        af[m] = *reinterpret_cast<const short8*>(lsA + row * 128 + (kb ^ ((row & 7) << 4)));
      }
#pragma unroll
      for (int n = 0; n < 4; ++n) {
        int row = wc * 64 + n * 16 + c16;
        int off = row * 128 + (kb ^ ((row & 7) << 4));
        b1[n] = *reinterpret_cast<const short8*>(lsB1 + off);
        b2[n] = *reinterpret_cast<const short8*>(lsB2 + off);
      }
#pragma unroll
      for (int m = 0; m < 4; ++m)
#pragma unroll
        for (int n = 0; n < 4; ++n) {
          a1[m][n] = __builtin_amdgcn_mfma_f32_16x16x32_bf16(af[m], b1[n], a1[m][n], 0, 0, 0);
          a3[m][n] = __builtin_amdgcn_mfma_f32_16x16x32_bf16(af[m], b2[n], a3[m][n], 0, 0, 0);
        }
    }
    __syncthreads();
  }
#pragma unroll
  for (int m = 0; m < 4; ++m) {
    int rb = m0 + wr * 64 + m * 16 + 4 * g16;
#pragma unroll
    for (int n = 0; n < 4; ++n) {
      int gc = n0 + wc * 64 + n * 16 + c16;
#pragma unroll
      for (int r = 0; r < 4; ++r) {
        int rbr = rb + r;
        if (rbr < cval) {
          float v1 = a1[m][n][r], v3 = a3[m][n][r];
          hg[(size_t)(obase + rbr) * F_ + gc] = __float2bfloat16(v1 / (1.f + __expf(-v1)) * v3);
        }
      }
    }
  }
}

// ---- MoE down, z-batched; writes compacted hgo rows (no atomics, rows disjoint) ----
__global__ __launch_bounds__(256) void k_moe2w(
    const bf16_t* __restrict__ hg, const bf16_t* __restrict__ w2t,
    bf16_t* __restrict__ hgo,
    const int* __restrict__ cnt8, const int* __restrict__ off8) {
  __shared__ __align__(16) char lds[2 * 16384];
  char* lsA = lds;
  char* lsB = lds + 16384;
  const int tid = threadIdx.x, l = tid & 63, g16 = l >> 4, c16 = l & 15;
  const int e = blockIdx.z;
  const int nbn = D_ >> 7;
  const int bm = (int)blockIdx.x / nbn, bn = (int)blockIdx.x % nbn;
  const int m0 = bm << 7, n0 = bn << 7;
  const int w = tid >> 6, wr = w >> 1, wc = w & 1;
  const int cval = cnt8[e];
  if (m0 >= cval) return;
  const int obase = off8[e];
  const bf16_t* Bt = w2t + (size_t)e * D_ * F_;

  f32x4 acc[4][4] = {};
  int Lb[4], sr[4], sk[4];
#pragma unroll
  for (int i = 0; i < 4; ++i) {
    Lb[i] = (tid + i * 256) * 16;
    sr[i] = Lb[i] >> 7;
    sk[i] = ((Lb[i] & 127) ^ ((sr[i] & 7) << 4)) >> 1;
  }
  for (int k0 = 0; k0 < F_; k0 += 64) {
#pragma unroll
    for (int i = 0; i < 4; ++i) {
      gl2lds16(hg + (size_t)(obase + m0 + sr[i]) * F_ + k0 + sk[i], lsA + Lb[i]);
      gl2lds16(Bt + (size_t)(n0 + sr[i]) * F_ + k0 + sk[i], lsB + Lb[i]);
    }
    __syncthreads();
#pragma unroll
    for (int kc = 0; kc < 2; ++kc) {
      const int kb = (kc * 32 + 8 * g16) * 2;
      short8 af[4], bf8[4];
#pragma unroll
      for (int m = 0; m < 4; ++m) {
        int row = wr * 64 + m * 16 + c16;
        af[m] = *reinterpret_cast<const short8*>(lsA + row * 128 + (kb ^ ((row & 7) << 4)));
      }
#pragma unroll
      for (int n = 0; n < 4; ++n) {
        int row = wc * 64 + n * 16 + c16;
        bf8[n] = *reinterpret_cast<const short8*>(lsB + row * 128 + (kb ^ ((row & 7) << 4)));
      }
#pragma unroll
      for (int m = 0; m < 4; ++m)
#pragma unroll
        for (int n = 0; n < 4; ++n)
          acc[m][n] = __builtin_amdgcn_mfma_f32_16x16x32_bf16(af[m], bf8[n], acc[m][n], 0, 0, 0);
    }
    __syncthreads();
  }
#pragma unroll
  for (int m = 0; m < 4; ++m) {
    int rb = m0 + wr * 64 + m * 16 + 4 * g16;
#pragma unroll
    for (int n = 0; n < 4; ++n) {
      int gc = n0 + wc * 64 + n * 16 + c16;
#pragma unroll
      for (int r = 0; r < 4; ++r) {
        int rbr = rb + r;
        if (rbr < cval)
          hgo[(size_t)(obase + rbr) * D_ + gc] = __float2bfloat16(acc[m][n][r]);
      }
    }
  }
}

// ---- causal flash attention: QBLK=256, 16 waves, split-3, vT-global, dbuf K/V, 1 barrier/tile ----
__global__ __launch_bounds__(1024) void k_flash16(
    const bf16_t* __restrict__ qh, const bf16_t* __restrict__ ql,
    const bf16_t* __restrict__ kbh, const bf16_t* __restrict__ kbl,
    const bf16_t* __restrict__ vth, const bf16_t* __restrict__ vtl,
    bf16_t* __restrict__ ch, bf16_t* __restrict__ cl, int zb) {
  __shared__ __align__(16) char lds[131072];
  const int tid = threadIdx.x, l = tid & 63, w = tid >> 6;  // 16 waves
  const int g16 = l >> 4, c16 = l & 15;
  const int qt = (int)gridDim.y - 1 - (int)blockIdx.y;  // LPT
  const int h = (int)blockIdx.x / zb;
  const int z = (int)blockIdx.x % zb;
  const int zS = z * S_;
  const size_t vz = (size_t)z * 2097152;

  const int qrow = qt * 256 + w * 16 + c16;
  const size_t qoff = (size_t)(zS + qrow) * 1536 + h * 64 + 8 * g16;
  const short8 aq0h = *reinterpret_cast<const short8*>(qh + qoff);
  const short8 aq1h = *reinterpret_cast<const short8*>(qh + qoff + 32);
  const short8 aq0l = *reinterpret_cast<const short8*>(ql + qoff);
  const short8 aq1l = *reinterpret_cast<const short8*>(ql + qoff + 32);

  float mrow[4] = {-3e38f, -3e38f, -3e38f, -3e38f};
  float lrow[4] = {0.f, 0.f, 0.f, 0.f};
  f32x4 o[4] = {};
  char* Pwh = lds + 65536 + w * 2048;
  char* Pwl = lds + 98304 + w * 2048;

  auto stage = [&](int buf, int kt) {
    char* base = lds + buf * 32768;
    int t2 = tid & 511;
    int Lb = t2 * 16;
    int r = Lb >> 7;
    int dd = ((Lb & 127) ^ ((r & 7) << 4)) >> 1;
    if (tid < 512) {
      size_t ko = (size_t)(zS + kt * 64 + r) * 1024 + h * 64 + dd;
      gl2lds16(kbh + ko, base + Lb);
      gl2lds16(kbl + ko, base + 8192 + Lb);
    } else {
      size_t vo = vz + (size_t)(h * 64 + r) * 2048 + kt * 64 + dd;
      gl2lds16(vth + vo, base + 16384 + Lb);
      gl2lds16(vtl + vo, base + 24576 + Lb);
    }
  };

  const int nkt = 4 * qt + 4;
  stage(0, 0);
  for (int kt = 0; kt < nkt; ++kt) {
    const int cb = kt & 1;
    char* Kh = lds + cb * 32768;
    char* Kl = Kh + 8192;
    char* Vh = Kh + 16384;
    char* Vl = Kh + 24576;
    __syncthreads();
    if (kt + 1 < nkt) stage(cb ^ 1, kt + 1);

    f32x4 s[4] = {};
#pragma unroll
    for (int kc = 0; kc < 2; ++kc) {
      const short8 ah8 = kc ? aq1h : aq0h;
      const short8 al8 = kc ? aq1l : aq0l;
      const int kb = (kc * 32 + 8 * g16) * 2;
#pragma unroll
      for (int n = 0; n < 4; ++n) {
        int row = n * 16 + c16;
        int off = row * 128 + (kb ^ ((row & 7) << 4));
        short8 bkh = *reinterpret_cast<const short8*>(Kh + off);
        short8 bkl = *reinterpret_cast<const short8*>(Kl + off);
        s[n] = __builtin_amdgcn_mfma_f32_16x16x32_bf16(al8, bkh, s[n], 0, 0, 0);
        s[n] = __builtin_amdgcn_mfma_f32_16x16x32_bf16(ah8, bkl, s[n], 0, 0, 0);
        s[n] = __builtin_amdgcn_mfma_f32_16x16x32_bf16(ah8, bkh, s[n], 0, 0, 0);
      }
    }

    const bool dreg = (kt >= 4 * qt);
#pragma unroll
    for (int r = 0; r < 4; ++r) {
      const int rowabs = qt * 256 + w * 16 + 4 * g16 + r;
      float mx = -3e38f;
#pragma unroll
      for (int n = 0; n < 4; ++n) {
        float sv = s[n][r] * 0.125f;
        if (dreg && (kt * 64 + n * 16 + c16 > rowabs)) sv = -3e38f;
        s[n][r] = sv;
        mx = fmaxf(mx, sv);
      }
      mx = fmaxf(mx, __shfl_xor(mx, 1, 64));
      mx = fmaxf(mx, __shfl_xor(mx, 2, 64));
      mx = fmaxf(mx, __shfl_xor(mx, 4, 64));
      mx = fmaxf(mx, __shfl_xor(mx, 8, 64));
      float mnew = fmaxf(mrow[r], mx);
      float alpha = __expf(mrow[r] - mnew);
      float rsum = 0.f;
#pragma unroll
      for (int n = 0; n < 4; ++n) {
        float pp = __expf(s[n][r] - mnew);
        s[n][r] = pp;
        rsum += pp;
      }
      rsum += __shfl_xor(rsum, 1, 64);
      rsum += __shfl_xor(rsum, 2, 64);
      rsum += __shfl_xor(rsum, 4, 64);
      rsum += __shfl_xor(rsum, 8, 64);
      lrow[r] = lrow[r] * alpha + rsum;
      mrow[r] = mnew;
#pragma unroll
      for (int n = 0; n < 4; ++n) o[n][r] *= alpha;
    }

#pragma unroll
    for (int n = 0; n < 4; ++n)
#pragma unroll
      for (int r = 0; r < 4; ++r) {
        int row = 4 * g16 + r, col = n * 16 + c16;
        int off = row * 128 + ((col * 2) ^ ((row & 7) << 4));
        bf16_t ph, pl; split2(s[n][r], ph, pl);
        *reinterpret_cast<unsigned short*>(Pwh + off) = bf16u(ph);
        *reinterpret_cast<unsigned short*>(Pwl + off) = bf16u(pl);
      }

#pragma unroll
    for (int kc = 0; kc < 2; ++kc) {
      const int kb = (kc * 32 + 8 * g16) * 2;
      int poff = c16 * 128 + (kb ^ ((c16 & 7) << 4));
      short8 aph = *reinterpret_cast<const short8*>(Pwh + poff);
      short8 apl = *reinterpret_cast<const short8*>(Pwl + poff);
#pragma unroll
      for (int n = 0; n < 4; ++n) {
        int dr = n * 16 + c16;
        int off = dr * 128 + (kb ^ ((dr & 7) << 4));
        short8 bvh = *reinterpret_cast<const short8*>(Vh + off);
        short8 bvl = *reinterpret_cast<const short8*>(Vl + off);
        o[n] = __builtin_amdgcn_mfma_f32_16x16x32_bf16(apl, bvh, o[n], 0, 0, 0);
        o[n] = __builtin_amdgcn_mfma_f32_16x16x32_bf16(aph, bvl, o[n], 0, 0, 0);
        o[n] = __builtin_amdgcn_mfma_f32_16x16x32_bf16(aph, bvh, o[n], 0, 0, 0);
      }
    }
  }

#pragma unroll
  for (int n = 0; n < 4; ++n)
#pragma unroll
    for (int r = 0; r < 4; ++r) {
      float val = o[n][r] / lrow[r];
      size_t idx = (size_t)(zS + qt * 256 + w * 16 + 4 * g16 + r) * 1024 + h * 64 + n * 16 + c16;
      bf16_t hh, ll; split2(val, hh, ll);
      ch[idx] = hh; cl[idx] = ll;
    }
}

extern "C" void kernel_launch(void* const* d_in, const int* in_sizes, int n_in,
                              void* d_out, int out_size, void* d_ws, size_t ws_size,
                              hipStream_t stream) {
  const size_t MB = 1ull << 20;

  // ---- input-order dispatch by size signature ----
  static const int dictSz[16] = {8388608, 8388608, 2097152, 1024, 1024, 1024, 1024,
                                 1048576, 524288, 524288, 524288, 1048576, 8192,
                                 16777216, 16777216, 16777216};
  static const int alphaSz[16] = {8388608, 1024, 1024, 1024, 1024, 8388608,
                                  16777216, 16777216, 16777216, 2097152, 524288,
                                  8192, 524288, 524288, 1048576, 1048576};
  bool isDict = (n_in == 16), isAlpha = (n_in == 16);
  for (int i = 0; i < 16; ++i) {
    if (n_in != 16) break;
    if (in_sizes[i] != dictSz[i]) isDict = false;
    if (in_sizes[i] != alphaSz[i]) isAlpha = false;
  }
  if ((!isDict && !isAlpha) || ws_size < 64 * MB) {
    k_fill<<<(out_size + 255) / 256, 256, 0, stream>>>((float*)d_out, 444.f, out_size);
    return;
  }

  const float *prev, *fut, *w_combine, *g1, *g2, *g_attn, *g_mlp, *wq, *w_dkv,
      *w_uk, *w_uv, *wo, *w_gate, *w1, *w3, *w2;
  if (isDict) {
    prev = (const float*)d_in[0];  fut = (const float*)d_in[1];
    w_combine = (const float*)d_in[2];
    g1 = (const float*)d_in[3];  g2 = (const float*)d_in[4];
    g_attn = (const float*)d_in[5];  g_mlp = (const float*)d_in[6];
    wq = (const float*)d_in[7];  w_dkv = (const float*)d_in[8];
    w_uk = (const float*)d_in[9];  w_uv = (const float*)d_in[10];
    wo = (const float*)d_in[11];  w_gate = (const float*)d_in[12];
    w1 = (const float*)d_in[13];  w3 = (const float*)d_in[14];
    w2 = (const float*)d_in[15];
  } else {
    fut = (const float*)d_in[0];
    g1 = (const float*)d_in[1];  g2 = (const float*)d_in[2];
    g_attn = (const float*)d_in[3];  g_mlp = (const float*)d_in[4];
    prev = (const float*)d_in[5];
    w1 = (const float*)d_in[6];  w2 = (const float*)d_in[7];  w3 = (const float*)d_in[8];
    w_combine = (const float*)d_in[9];  w_dkv = (const float*)d_in[10];
    w_gate = (const float*)d_in[11];  w_uk = (const float*)d_in[12];
    w_uv = (const float*)d_in[13];  wo = (const float*)d_in[14];
    wq = (const float*)d_in[15];
  }

  float* hid = (float*)d_out;
  char* ws = (char*)d_ws;
  const bool big = (ws_size >= 192 * MB);

  // ---- weights (era-scoped) @ [0,14) ----
  bf16_t* wcth = (bf16_t*)(ws + 0 * MB);
  bf16_t* wctl = (bf16_t*)(ws + 4 * MB);
  bf16_t* qcTh = (bf16_t*)(ws + 0 * MB);
  bf16_t* qcTl = (bf16_t*)(ws + 3 * MB);
  bf16_t* kvTh = (bf16_t*)(ws + 6 * MB);
  bf16_t* kvTl = (bf16_t*)(ws + 8 * MB);
  bf16_t* woth = (bf16_t*)(ws + 10 * MB);
  bf16_t* wotl = (bf16_t*)(ws + 12 * MB);
  bf16_t* w1t  = (bf16_t*)(ws + 0 * MB);   // small path only
  bf16_t* w3t  = (bf16_t*)(ws + 4 * MB);
  bf16_t* w2t  = (bf16_t*)(ws + 8 * MB);
  float*  gates = (float*)(ws + 14 * MB);                    // 256KB
  int*    idx   = (int*)(ws + 14 * MB + 262144);             // 256KB
  int*    pos8  = (int*)(ws + 14 * MB + 524288);             // 256KB
  int*    cnt   = (int*)(ws + 14 * MB + 786432);             // 32B
  int*    off   = (int*)(ws + 14 * MB + 786432 + 64);        // 32B
  bf16_t* xnh = (bf16_t*)(ws + 15 * MB);

  dim3 tb(32, 8);

  if (big) {
    // ================= fully batched path (peak 191 MiB) =================
    bf16_t* xcath = (bf16_t*)(ws + 15 * MB);
    bf16_t* xcatl = (bf16_t*)(ws + 47 * MB);
    bf16_t* xnbh  = (bf16_t*)(ws + 15 * MB);
    bf16_t* xnbl  = (bf16_t*)(ws + 31 * MB);
    bf16_t* qch   = (bf16_t*)(ws + 47 * MB);
    bf16_t* qcl   = (bf16_t*)(ws + 71 * MB);
    bf16_t* kbh   = (bf16_t*)(ws + 95 * MB);
    bf16_t* kbl   = (bf16_t*)(ws + 111 * MB);
    bf16_t* vth   = (bf16_t*)(ws + 127 * MB);
    bf16_t* vtl   = (bf16_t*)(ws + 143 * MB);
    bf16_t* ctxh  = (bf16_t*)(ws + 159 * MB);
    bf16_t* ctxl  = (bf16_t*)(ws + 175 * MB);
    // MoE era overlays (after attn consumed)
    bf16_t* hg    = (bf16_t*)(ws + 31 * MB);   // 64 MB  [2T][F]
    bf16_t* hgo   = (bf16_t*)(ws + 95 * MB);   // 32 MB  [2T][D] (w1tA dead by moe2)
    bf16_t* w1tA  = (bf16_t*)(ws + 95 * MB);   // 32 MB (moe1 era only)
    bf16_t* w3tA  = (bf16_t*)(ws + 127 * MB);  // 32 MB
    bf16_t* w2tA  = (bf16_t*)(ws + 159 * MB);  // 32 MB

    // combine era
    k_transpose2<<<dim3(32, 64), tb, 0, stream>>>(w_combine, wcth, wctl, 2 * D_, D_, D_);
    k_rms2cat2<<<T_, 256, 0, stream>>>(prev, fut, g1, g2, xcath, xcatl);
    k_sgemm<0, 3, 0><<<dim3(64 * 8), 256, 0, stream>>>(
        xcath, xcatl, wcth, wctl, hid, nullptr, nullptr, nullptr, nullptr,
        nullptr, nullptr, nullptr, D_, 2 * D_, 2 * D_, D_);

    // attn era
    k_transpose2<<<dim3(32, 32), tb, 0, stream>>>(wq, qcTh, qcTl, D_, D_, D_);
    k_transpose2<<<dim3(16, 32), tb, 0, stream>>>(w_dkv, qcTh + 1024 * 1024, qcTl + 1024 * 1024, D_, L_, L_);
    k_transpose2<<<dim3(32, 16), tb, 0, stream>>>(w_uk, kvTh, kvTl, L_, D_, D_);
    k_transpose2<<<dim3(32, 16), tb, 0, stream>>>(w_uv, kvTh + 1024 * 512, kvTl + 1024 * 512, L_, D_, D_);
    k_transpose2<<<dim3(32, 32), tb, 0, stream>>>(wo, woth, wotl, D_, D_, D_);
    k_rmsnorm2<<<T_, 256, 0, stream>>>(hid, g_attn, xnbh, xnbl);
    k_sgemm<2, 3, 0><<<dim3(64 * 12), 256, 0, stream>>>(
        xnbh, xnbl, qcTh, qcTl, nullptr, qch, qcl, nullptr, nullptr,
        nullptr, nullptr, nullptr, 1536, D_, D_, 1536);
    k_sgemm<7, 3, 0><<<dim3(64 * 16), 256, 0, stream>>>(
        qch + 1024, qcl + 1024, kvTh, kvTl, nullptr, kbh, kbl, vth, vtl,
        nullptr, nullptr, nullptr, 2048, L_, 1536, 1024);
    k_flash16<<<dim3(H_ * B_, 8, 1), 1024, 0, stream>>>(qch, qcl, kbh, kbl, vth, vtl, ctxh, ctxl, B_);
    k_sgemm<1, 3, 0><<<dim3(64 * 8), 256, 0, stream>>>(
        ctxh, ctxl, woth, wotl, hid, nullptr, nullptr, nullptr, nullptr,
        nullptr, nullptr, nullptr, D_, D_, D_, D_);

    // MoE era (sparse top-2; deterministic routing; batched weights; atomic-free down)
    k_rmsgate<<<T_, 256, 0, stream>>>(hid, g_mlp, w_gate, xnh, gates);
    k_route_det<<<E_, 256, 0, stream>>>(gates, idx, cnt, pos8);
    k_prefix<<<1, 1, 0, stream>>>(cnt, off);
    k_transpose_pair<<<dim3(64, 32, 16), tb, 0, stream>>>(w1, w3, w1tA, w3tA, D_, F_, F_,
                                                          (size_t)D_ * F_, (size_t)F_ * D_);
    k_transpose<<<dim3(32, 64, 8), tb, 0, stream>>>(w2, w2tA, F_, D_, D_, (size_t)F_ * D_, (size_t)D_ * F_);
    k_moe1<<<dim3(64 * 16, 1, 8), 256, 0, stream>>>(xnh, w1tA, w3tA, hg, idx, cnt, off);
    k_moe2w<<<dim3(64 * 8, 1, 8), 256, 0, stream>>>(hg, w2tA, hgo, cnt, off);
    k_moesum<<<T_, 256, 0, stream>>>(hid, hgo, gates, pos8, off);
  } else {
    // ================= per-batch fallback path (peak 63 MiB) =================
    bf16_t* xcath = (bf16_t*)(ws + 15 * MB);
    bf16_t* xcatl = (bf16_t*)(ws + 23 * MB);
    bf16_t* xnbh  = (bf16_t*)(ws + 15 * MB);
    bf16_t* xnbl  = (bf16_t*)(ws + 19 * MB);
    bf16_t* qch   = (bf16_t*)(ws + 23 * MB);
    bf16_t* qcl   = (bf16_t*)(ws + 29 * MB);
    bf16_t* kbh   = (bf16_t*)(ws + 35 * MB);
    bf16_t* kbl   = (bf16_t*)(ws + 39 * MB);
    bf16_t* vth   = (bf16_t*)(ws + 43 * MB);
    bf16_t* vtl   = (bf16_t*)(ws + 47 * MB);
    bf16_t* ctxh  = (bf16_t*)(ws + 51 * MB);
    bf16_t* ctxl  = (bf16_t*)(ws + 55 * MB);
    bf16_t* hg    = (bf16_t*)(ws + 31 * MB);

    k_transpose2<<<dim3(32, 64), tb, 0, stream>>>(w_combine, wcth, wctl, 2 * D_, D_, D_);
    for (int b = 0; b < B_; ++b) {
      size_t ro = (size_t)b * S_ * D_;
      k_rms2cat2<<<S_, 256, 0, stream>>>(prev + ro, fut + ro, g1, g2, xcath, xcatl);
      k_sgemm<0, 3, 0><<<dim3(16 * 8), 256, 0, stream>>>(
          xcath, xcatl, wcth, wctl, hid + ro, nullptr, nullptr, nullptr, nullptr,
          nullptr, nullptr, nullptr, D_, 2 * D_, 2 * D_, D_);
    }
    k_transpose2<<<dim3(32, 32), tb, 0, stream>>>(wq, qcTh, qcTl, D_, D_, D_);
    k_transpose2<<<dim3(16, 32), tb, 0, stream>>>(w_dkv, qcTh + 1024 * 1024, qcTl + 1024 * 1024, D_, L_, L_);
    k_transpose2<<<dim3(32, 16), tb, 0, stream>>>(w_uk, kvTh, kvTl, L_, D_, D_);
    k_transpose2<<<dim3(32, 16), tb, 0, stream>>>(w_uv, kvTh + 1024 * 512, kvTl + 1024 * 512, L_, D_, D_);
    k_transpose2<<<dim3(32, 32), tb, 0, stream>>>(wo, woth, wotl, D_, D_, D_);
    for (int b = 0; b < B_; ++b) {
      size_t ro = (size_t)b * S_ * D_;
      k_rmsnorm2<<<S_, 256, 0, stream>>>(hid + ro, g_attn, xnbh, xnbl);
      k_sgemm<2, 3, 0><<<dim3(16 * 12), 256, 0, stream>>>(
          xnbh, xnbl, qcTh, qcTl, nullptr, qch, qcl, nullptr, nullptr,
          nullptr, nullptr, nullptr, 1536, D_, D_, 1536);
      k_sgemm<7, 3, 0><<<dim3(16 * 16), 256, 0, stream>>>(
          qch + 1024, qcl + 1024, kvTh, kvTl, nullptr, kbh, kbl, vth, vtl,
          nullptr, nullptr, nullptr, 2048, L_, 1536, 1024);
      k_flash16<<<dim3(H_, 8, 1), 1024, 0, stream>>>(qch, qcl, kbh, kbl, vth, vtl, ctxh, ctxl, 1);
      k_sgemm<1, 3, 0><<<dim3(16 * 8), 256, 0, stream>>>(
          ctxh, ctxl, woth, wotl, hid + ro, nullptr, nullptr, nullptr, nullptr,
          nullptr, nullptr, nullptr, D_, D_, D_, D_);
    }
    k_rmsgate<<<T_, 256, 0, stream>>>(hid, g_mlp, w_gate, xnh, gates);
    k_route_det<<<E_, 256, 0, stream>>>(gates, idx, cnt, pos8);
    k_prefix<<<1, 1, 0, stream>>>(cnt, off);
    for (int e = 0; e < E_; ++e) {
      const int* ide = idx + e * T_;
      const int* cne = cnt + e;
      k_transpose<<<dim3(64, 32, 1), tb, 0, stream>>>(w1 + (size_t)e * D_ * F_, w1t, D_, F_, F_, 0, 0);
      k_transpose<<<dim3(64, 32, 1), tb, 0, stream>>>(w3 + (size_t)e * D_ * F_, w3t, D_, F_, F_, 0, 0);
      k_transpose<<<dim3(32, 64, 1), tb, 0, stream>>>(w2 + (size_t)e * F_ * D_, w2t, F_, D_, D_, 0, 0);
      k_sgemm<3, 1, 1><<<dim3(64 * 16), 256, 0, stream>>>(
          xnh, nullptr, w1t, nullptr, nullptr, hg, nullptr, nullptr, nullptr,
          nullptr, ide, cne, F_, D_, D_, F_);
      k_sgemm<4, 1, 1><<<dim3(64 * 16), 256, 0, stream>>>(
          xnh, nullptr, w3t, nullptr, nullptr, hg, nullptr, nullptr, nullptr,
          nullptr, ide, cne, F_, D_, D_, F_);
      k_sgemm<6, 1, 0><<<dim3(64 * 8), 256, 0, stream>>>(
          hg, nullptr, w2t, nullptr, hid, nullptr, nullptr, nullptr, nullptr,
          gates + e, ide, cne, D_, F_, F_, D_);
    }
  }
}